// Round 15
// baseline (374.662 us; speedup 1.0000x reference)
//
#include <hip/hip_runtime.h>

using short8 = __attribute__((ext_vector_type(8))) short;
using f32x4  = __attribute__((ext_vector_type(4))) float;

constexpr int HD = 128;
constexpr int NBLK_SCAT = 2048;   // scatter (deg/fill) blocks: 8 XCD groups x 256

__device__ __forceinline__ unsigned short f2bf(float f) {
    unsigned u = __builtin_bit_cast(unsigned, f);
    u += 0x7fffu + ((u >> 16) & 1u);          // round-to-nearest-even
    return (unsigned short)(u >> 16);
}
__device__ __forceinline__ float bflo(unsigned u) { return __builtin_bit_cast(float, u << 16); }
__device__ __forceinline__ float bfhi(unsigned u) { return __builtin_bit_cast(float, u & 0xffff0000u); }

__device__ __forceinline__ short8 ldg8(const unsigned short* p) {
    return *reinterpret_cast<const short8*>(p);   // 16B contiguous, aligned
}

// ---------------------------------------------------------------------------
// Chain GEMM body (256-thread, used inside k_u2): Out = (relu(A@Wt1+b1))@Wtc+b2
// ---------------------------------------------------------------------------
template<int NC2, bool F32OUT>
__device__ __forceinline__ void dev_chain(unsigned short* As1, unsigned short* Hs,
    const unsigned short* __restrict__ A, const unsigned short* __restrict__ Wt1,
    const unsigned short* __restrict__ Wtc, const float* __restrict__ b1,
    const float* __restrict__ b2, void* __restrict__ Out, int nrows, int bid)
{
    const int tid  = threadIdx.x;
    const int lane = tid & 63, wave = tid >> 6;
    const int lr = lane & 15, lg = lane >> 4;
    const int row0 = bid * 64;

#pragma unroll
    for (int it = 0; it < 4; ++it) {
        const int q   = wave * 4 + it;
        const int c   = q * 64 + lane;
        const int row = c >> 4, cw = c & 15;
        int grow = row0 + row; grow = grow < nrows ? grow : nrows - 1;
        const int gco = (cw ^ (row & 7)) << 3;
        __builtin_amdgcn_global_load_lds((const unsigned int*)(A + (long)grow * HD + gco),
                                         (unsigned int*)&As1[q * 512], 16, 0, 0);
    }

    const int cb1 = wave * 32;
    short8 bf1[2][4];
#pragma unroll
    for (int ct = 0; ct < 2; ++ct) {
        const unsigned short* bp = Wt1 + (long)(cb1 + ct * 16 + lr) * HD + lg * 8;
#pragma unroll
        for (int kt = 0; kt < 4; ++kt) bf1[ct][kt] = ldg8(bp + kt * 32);
    }
    constexpr int CT2 = NC2 / 64;
    const int cb2 = wave * (NC2 / 4);
    short8 bfc[CT2][4];
#pragma unroll
    for (int ct = 0; ct < CT2; ++ct) {
        const unsigned short* bp = Wtc + (long)(cb2 + ct * 16 + lr) * HD + lg * 8;
#pragma unroll
        for (int kt = 0; kt < 4; ++kt) bfc[ct][kt] = ldg8(bp + kt * 32);
    }

    __syncthreads();

    f32x4 acc[4][2] = {};
#pragma unroll
    for (int kt = 0; kt < 4; ++kt) {
        short8 af[4];
#pragma unroll
        for (int rt = 0; rt < 4; ++rt)
            af[rt] = *reinterpret_cast<const short8*>(
                &As1[(rt * 16 + lr) * HD + (((kt * 4 + lg) ^ (lr & 7)) << 3)]);
#pragma unroll
        for (int rt = 0; rt < 4; ++rt)
#pragma unroll
            for (int ct = 0; ct < 2; ++ct)
                acc[rt][ct] = __builtin_amdgcn_mfma_f32_16x16x32_bf16(af[rt], bf1[ct][kt], acc[rt][ct], 0, 0, 0);
    }

    const float bv1[2] = { b1[cb1 + lr], b1[cb1 + 16 + lr] };
#pragma unroll
    for (int rt = 0; rt < 4; ++rt)
#pragma unroll
        for (int ct = 0; ct < 2; ++ct) {
            const int cc = cb1 + ct * 16 + lr;
#pragma unroll
            for (int i = 0; i < 4; ++i) {
                const int row = rt * 16 + lg * 4 + i;
                const float v = fmaxf(acc[rt][ct][i] + bv1[ct], 0.f);
                Hs[row * HD + ((((cc >> 3) ^ (row & 7)) << 3) | (cc & 7))] = f2bf(v);
            }
        }
    __syncthreads();

    f32x4 acc2[4][CT2] = {};
#pragma unroll
    for (int kt = 0; kt < 4; ++kt) {
        short8 ah[4];
#pragma unroll
        for (int rt = 0; rt < 4; ++rt)
            ah[rt] = *reinterpret_cast<const short8*>(
                &Hs[(rt * 16 + lr) * HD + (((kt * 4 + lg) ^ (lr & 7)) << 3)]);
#pragma unroll
        for (int rt = 0; rt < 4; ++rt)
#pragma unroll
            for (int ct = 0; ct < CT2; ++ct)
                acc2[rt][ct] = __builtin_amdgcn_mfma_f32_16x16x32_bf16(ah[rt], bfc[ct][kt], acc2[rt][ct], 0, 0, 0);
    }
    float bv2[CT2];
#pragma unroll
    for (int ct = 0; ct < CT2; ++ct) bv2[ct] = b2[cb2 + ct * 16 + lr];
#pragma unroll
    for (int rt = 0; rt < 4; ++rt)
#pragma unroll
        for (int ct = 0; ct < CT2; ++ct) {
            const int cc = cb2 + ct * 16 + lr;
#pragma unroll
            for (int i = 0; i < 4; ++i) {
                const int r = row0 + rt * 16 + lg * 4 + i;
                if (r < nrows) {
                    const float v = acc2[rt][ct][i] + bv2[ct];
                    if constexpr (F32OUT) ((float*)Out)[(long)r * NC2 + cc] = v;
                    else ((unsigned short*)Out)[(long)r * NC2 + cc] = f2bf(v);
                }
            }
        }
}

// ---------------------------------------------------------------------------
// Merged dual + next-layer chain, 512-thread (8-wave) blocks, 64x128 tile,
// 3 LDS buffers (48KB). Wave w: row-half (w>>2), col-quarter (w&3) -> per-phase
// work per wave halves vs 4-wave version; waves/CU doubles for latency hiding.
//   phase1: x' = relu(Ag@WtL + Xs@WtR + bl) -> Ts + Xout global
//   phase2: h  = relu(Ts@Wt1 + b1) -> Ag
//   phase3: g  = Ag@Wtc + b2 -> Gout global
// Caller guarantees Xout/Gout do not alias Agg/X.
// ---------------------------------------------------------------------------
__global__ __launch_bounds__(512, 4)
void k_dualchain(const unsigned short* __restrict__ Agg, const unsigned short* __restrict__ X,
                 const unsigned short* __restrict__ WtL, const unsigned short* __restrict__ WtR,
                 const float* __restrict__ bl_,
                 const unsigned short* __restrict__ Wt1, const float* __restrict__ b1,
                 const unsigned short* __restrict__ Wtc, const float* __restrict__ b2,
                 unsigned short* __restrict__ Xout, unsigned short* __restrict__ Gout, int n)
{
    __shared__ __align__(16) unsigned short Ag[64 * HD];
    __shared__ __align__(16) unsigned short Xs[64 * HD];
    __shared__ __align__(16) unsigned short Ts[64 * HD];

    const int tid  = threadIdx.x;
    const int lane = tid & 63, wave = tid >> 6;
    const int lr = lane & 15, lg = lane >> 4;
    const int wr = wave >> 2;            // row half (0..1)
    const int cb = (wave & 3) * 32;      // col quarter base
    const int row0 = blockIdx.x * 64;

#pragma unroll
    for (int it = 0; it < 2; ++it) {
        const int q   = wave * 2 + it;          // 1KB chunk id 0..15
        const int c   = q * 64 + lane;          // 16B chunk id 0..1023
        const int row = c >> 4, cw = c & 15;
        int grow = row0 + row; grow = grow < n ? grow : n - 1;
        const int gco = (cw ^ (row & 7)) << 3;
        __builtin_amdgcn_global_load_lds((const unsigned int*)(Agg + (long)grow * HD + gco),
                                         (unsigned int*)&Ag[q * 512], 16, 0, 0);
        __builtin_amdgcn_global_load_lds((const unsigned int*)(X + (long)grow * HD + gco),
                                         (unsigned int*)&Xs[q * 512], 16, 0, 0);
    }

    short8 bl[2][4], br[2][4];
#pragma unroll
    for (int ct = 0; ct < 2; ++ct) {
        const long roff = (long)(cb + ct * 16 + lr) * HD + lg * 8;
#pragma unroll
        for (int kt = 0; kt < 4; ++kt) { bl[ct][kt] = ldg8(WtL + roff + kt * 32); br[ct][kt] = ldg8(WtR + roff + kt * 32); }
    }
    __syncthreads();   // (1) DMA + weights drained

    // phase 1: x' = relu(Ag@WtL + Xs@WtR + bl) -> Ts + Xout
    f32x4 acc[2][2] = {};
#pragma unroll
    for (int kt = 0; kt < 4; ++kt) {
        short8 aa[2], ax[2];
#pragma unroll
        for (int rt = 0; rt < 2; ++rt) {
            const int lrow = wr * 32 + rt * 16 + lr;
            const int base = lrow * HD + (((kt * 4 + lg) ^ (lrow & 7)) << 3);
            aa[rt] = *reinterpret_cast<const short8*>(&Ag[base]);
            ax[rt] = *reinterpret_cast<const short8*>(&Xs[base]);
        }
#pragma unroll
        for (int rt = 0; rt < 2; ++rt)
#pragma unroll
            for (int ct = 0; ct < 2; ++ct) {
                acc[rt][ct] = __builtin_amdgcn_mfma_f32_16x16x32_bf16(aa[rt], bl[ct][kt], acc[rt][ct], 0, 0, 0);
                acc[rt][ct] = __builtin_amdgcn_mfma_f32_16x16x32_bf16(ax[rt], br[ct][kt], acc[rt][ct], 0, 0, 0);
            }
    }
    // issue phase-2 weights (hide under epilogue + barrier)
    short8 b1f[2][4];
#pragma unroll
    for (int ct = 0; ct < 2; ++ct) {
        const unsigned short* bp = Wt1 + (long)(cb + ct * 16 + lr) * HD + lg * 8;
#pragma unroll
        for (int kt = 0; kt < 4; ++kt) b1f[ct][kt] = ldg8(bp + kt * 32);
    }
    {
        const float bv[2] = { bl_[cb + lr], bl_[cb + 16 + lr] };
#pragma unroll
        for (int rt = 0; rt < 2; ++rt)
#pragma unroll
            for (int ct = 0; ct < 2; ++ct) {
                const int cc = cb + ct * 16 + lr;
#pragma unroll
                for (int i = 0; i < 4; ++i) {
                    const int row = wr * 32 + rt * 16 + lg * 4 + i;
                    const int r = row0 + row;
                    const float v = fmaxf(acc[rt][ct][i] + bv[ct], 0.f);
                    const unsigned short vb = f2bf(v);
                    Ts[row * HD + ((((cc >> 3) ^ (row & 7)) << 3) | (cc & 7))] = vb;
                    if (r < n) Xout[(long)r * HD + cc] = vb;
                }
            }
    }
    __syncthreads();   // (2) Ts visible; all Ag/Xs reads done

    // phase 2: h = relu(Ts@Wt1 + b1) -> Ag
    {
        f32x4 a2[2][2] = {};
#pragma unroll
        for (int kt = 0; kt < 4; ++kt) {
            short8 ah[2];
#pragma unroll
            for (int rt = 0; rt < 2; ++rt) {
                const int lrow = wr * 32 + rt * 16 + lr;
                ah[rt] = *reinterpret_cast<const short8*>(
                    &Ts[lrow * HD + (((kt * 4 + lg) ^ (lrow & 7)) << 3)]);
            }
#pragma unroll
            for (int rt = 0; rt < 2; ++rt)
#pragma unroll
                for (int ct = 0; ct < 2; ++ct)
                    a2[rt][ct] = __builtin_amdgcn_mfma_f32_16x16x32_bf16(ah[rt], b1f[ct][kt], a2[rt][ct], 0, 0, 0);
        }
        // issue phase-3 weights
        short8 bcf[2][4];
#pragma unroll
        for (int ct = 0; ct < 2; ++ct) {
            const unsigned short* bp = Wtc + (long)(cb + ct * 16 + lr) * HD + lg * 8;
#pragma unroll
            for (int kt = 0; kt < 4; ++kt) bcf[ct][kt] = ldg8(bp + kt * 32);
        }
        const float bv[2] = { b1[cb + lr], b1[cb + 16 + lr] };
#pragma unroll
        for (int rt = 0; rt < 2; ++rt)
#pragma unroll
            for (int ct = 0; ct < 2; ++ct) {
                const int cc = cb + ct * 16 + lr;
#pragma unroll
                for (int i = 0; i < 4; ++i) {
                    const int row = wr * 32 + rt * 16 + lg * 4 + i;
                    const float v = fmaxf(a2[rt][ct][i] + bv[ct], 0.f);
                    Ag[row * HD + ((((cc >> 3) ^ (row & 7)) << 3) | (cc & 7))] = f2bf(v);
                }
            }
        __syncthreads();   // (3) h visible

        // phase 3: g = Ag@Wtc + b2 -> Gout
        f32x4 a3[2][2] = {};
#pragma unroll
        for (int kt = 0; kt < 4; ++kt) {
            short8 ah[2];
#pragma unroll
            for (int rt = 0; rt < 2; ++rt) {
                const int lrow = wr * 32 + rt * 16 + lr;
                ah[rt] = *reinterpret_cast<const short8*>(
                    &Ag[lrow * HD + (((kt * 4 + lg) ^ (lrow & 7)) << 3)]);
            }
#pragma unroll
            for (int rt = 0; rt < 2; ++rt)
#pragma unroll
                for (int ct = 0; ct < 2; ++ct)
                    a3[rt][ct] = __builtin_amdgcn_mfma_f32_16x16x32_bf16(ah[rt], bcf[ct][kt], a3[rt][ct], 0, 0, 0);
        }
        const float bv2[2] = { b2[cb + lr], b2[cb + 16 + lr] };
#pragma unroll
        for (int rt = 0; rt < 2; ++rt)
#pragma unroll
            for (int ct = 0; ct < 2; ++ct) {
                const int cc = cb + ct * 16 + lr;
#pragma unroll
                for (int i = 0; i < 4; ++i) {
                    const int r = row0 + wr * 32 + rt * 16 + lg * 4 + i;
                    if (r < n) Gout[(long)r * HD + cc] = f2bf(a3[rt][ct][i] + bv2[ct]);
                }
            }
    }
}

// ---------------------------------------------------------------------------
// Merged dual + decoder, 512-thread blocks, same wave decomposition.
//   phase1: x3 = relu(Ag@WtL + Xs@WtR + bl) -> Ts
//   phase2: emb = relu(Ts@Wdec + bdec) -> Ag
//   phase3: logits = Ag@Wfin + bfin -> f32 (wave w: coltile w&3, rowtiles (w>>2)*2+{0,1})
// ---------------------------------------------------------------------------
__global__ __launch_bounds__(512, 4)
void k_dualdec(const unsigned short* __restrict__ Agg, const unsigned short* __restrict__ X,
               const unsigned short* __restrict__ WtL, const unsigned short* __restrict__ WtR,
               const float* __restrict__ bl_, const unsigned short* __restrict__ Wdec,
               const float* __restrict__ bdec, const unsigned short* __restrict__ Wfin,
               const float* __restrict__ bfin, float* __restrict__ Out, int n)
{
    __shared__ __align__(16) unsigned short Ag[64 * HD];
    __shared__ __align__(16) unsigned short Xs[64 * HD];
    __shared__ __align__(16) unsigned short Ts[64 * HD];

    const int tid  = threadIdx.x;
    const int lane = tid & 63, wave = tid >> 6;
    const int lr = lane & 15, lg = lane >> 4;
    const int wr = wave >> 2;
    const int cb = (wave & 3) * 32;
    const int row0 = blockIdx.x * 64;

#pragma unroll
    for (int it = 0; it < 2; ++it) {
        const int q   = wave * 2 + it;
        const int c   = q * 64 + lane;
        const int row = c >> 4, cw = c & 15;
        int grow = row0 + row; grow = grow < n ? grow : n - 1;
        const int gco = (cw ^ (row & 7)) << 3;
        __builtin_amdgcn_global_load_lds((const unsigned int*)(Agg + (long)grow * HD + gco),
                                         (unsigned int*)&Ag[q * 512], 16, 0, 0);
        __builtin_amdgcn_global_load_lds((const unsigned int*)(X + (long)grow * HD + gco),
                                         (unsigned int*)&Xs[q * 512], 16, 0, 0);
    }

    short8 bl[2][4], br[2][4];
#pragma unroll
    for (int ct = 0; ct < 2; ++ct) {
        const long roff = (long)(cb + ct * 16 + lr) * HD + lg * 8;
#pragma unroll
        for (int kt = 0; kt < 4; ++kt) { bl[ct][kt] = ldg8(WtL + roff + kt * 32); br[ct][kt] = ldg8(WtR + roff + kt * 32); }
    }
    __syncthreads();   // (1)

    // phase 1: x3 -> Ts
    f32x4 acc[2][2] = {};
#pragma unroll
    for (int kt = 0; kt < 4; ++kt) {
        short8 aa[2], ax[2];
#pragma unroll
        for (int rt = 0; rt < 2; ++rt) {
            const int lrow = wr * 32 + rt * 16 + lr;
            const int base = lrow * HD + (((kt * 4 + lg) ^ (lrow & 7)) << 3);
            aa[rt] = *reinterpret_cast<const short8*>(&Ag[base]);
            ax[rt] = *reinterpret_cast<const short8*>(&Xs[base]);
        }
#pragma unroll
        for (int rt = 0; rt < 2; ++rt)
#pragma unroll
            for (int ct = 0; ct < 2; ++ct) {
                acc[rt][ct] = __builtin_amdgcn_mfma_f32_16x16x32_bf16(aa[rt], bl[ct][kt], acc[rt][ct], 0, 0, 0);
                acc[rt][ct] = __builtin_amdgcn_mfma_f32_16x16x32_bf16(ax[rt], br[ct][kt], acc[rt][ct], 0, 0, 0);
            }
    }
    short8 bd[2][4];
#pragma unroll
    for (int ct = 0; ct < 2; ++ct) {
        const unsigned short* bp = Wdec + (long)(cb + ct * 16 + lr) * HD + lg * 8;
#pragma unroll
        for (int kt = 0; kt < 4; ++kt) bd[ct][kt] = ldg8(bp + kt * 32);
    }
    {
        const float bv[2] = { bl_[cb + lr], bl_[cb + 16 + lr] };
#pragma unroll
        for (int rt = 0; rt < 2; ++rt)
#pragma unroll
            for (int ct = 0; ct < 2; ++ct) {
                const int cc = cb + ct * 16 + lr;
#pragma unroll
                for (int i = 0; i < 4; ++i) {
                    const int row = wr * 32 + rt * 16 + lg * 4 + i;
                    const float v = fmaxf(acc[rt][ct][i] + bv[ct], 0.f);
                    Ts[row * HD + ((((cc >> 3) ^ (row & 7)) << 3) | (cc & 7))] = f2bf(v);
                }
            }
    }
    __syncthreads();   // (2)

    // phase 2: emb = relu(Ts@Wdec + bdec) -> Ag
    {
        f32x4 a2[2][2] = {};
#pragma unroll
        for (int kt = 0; kt < 4; ++kt) {
            short8 ah[2];
#pragma unroll
            for (int rt = 0; rt < 2; ++rt) {
                const int lrow = wr * 32 + rt * 16 + lr;
                ah[rt] = *reinterpret_cast<const short8*>(
                    &Ts[lrow * HD + (((kt * 4 + lg) ^ (lrow & 7)) << 3)]);
            }
#pragma unroll
            for (int rt = 0; rt < 2; ++rt)
#pragma unroll
                for (int ct = 0; ct < 2; ++ct)
                    a2[rt][ct] = __builtin_amdgcn_mfma_f32_16x16x32_bf16(ah[rt], bd[ct][kt], a2[rt][ct], 0, 0, 0);
        }
        const int cbf = (wave & 3) * 16;
        short8 bfn[4];
#pragma unroll
        for (int kt = 0; kt < 4; ++kt)
            bfn[kt] = ldg8(Wfin + (long)(cbf + lr) * HD + lg * 8 + kt * 32);
        const float bv[2] = { bdec[cb + lr], bdec[cb + 16 + lr] };
#pragma unroll
        for (int rt = 0; rt < 2; ++rt)
#pragma unroll
            for (int ct = 0; ct < 2; ++ct) {
                const int cc = cb + ct * 16 + lr;
#pragma unroll
                for (int i = 0; i < 4; ++i) {
                    const int row = wr * 32 + rt * 16 + lg * 4 + i;
                    const float v = fmaxf(a2[rt][ct][i] + bv[ct], 0.f);
                    Ag[row * HD + ((((cc >> 3) ^ (row & 7)) << 3) | (cc & 7))] = f2bf(v);
                }
            }
        __syncthreads();   // (3)

        // phase 3: logits = Ag@Wfin + bfin (64 cols; wave -> coltile w&3, 2 rowtiles)
        f32x4 a3[2] = {};
#pragma unroll
        for (int kt = 0; kt < 4; ++kt) {
            short8 ah[2];
#pragma unroll
            for (int rt = 0; rt < 2; ++rt) {
                const int lrow = (wr * 2 + rt) * 16 + lr;
                ah[rt] = *reinterpret_cast<const short8*>(
                    &Ag[lrow * HD + (((kt * 4 + lg) ^ (lrow & 7)) << 3)]);
            }
#pragma unroll
            for (int rt = 0; rt < 2; ++rt)
                a3[rt] = __builtin_amdgcn_mfma_f32_16x16x32_bf16(ah[rt], bfn[kt], a3[rt], 0, 0, 0);
        }
        const float bvf = bfin[cbf + lr];
#pragma unroll
        for (int rt = 0; rt < 2; ++rt)
#pragma unroll
            for (int i = 0; i < 4; ++i) {
                const int r = row0 + (wr * 2 + rt) * 16 + lg * 4 + i;
                if (r < n) Out[(long)r * 64 + cbf + lr] = a3[rt][i] + bvf;
            }
    }
}

// ---- scatter bodies (XCD-affine: 8 node-chunks, group = bid&7) ----
__device__ __forceinline__ void dev_deg(const int* __restrict__ dst, int* __restrict__ deg,
                                        int nE, int n, int bid, int nblk) {
    const int grp = bid & 7, bin = bid >> 3, nbin = nblk >> 3;
    const int chunk = (n + 7) >> 3;
    const int lo = grp * chunk, hi = min(n, lo + chunk);
    for (int e = bin * 256 + threadIdx.x; e < nE; e += nbin * 256) {
        const int d = dst[e];
        if (d >= lo && d < hi) atomicAdd(&deg[d], 1);
    }
}

__device__ __forceinline__ void dev_fill(const int* __restrict__ src, const int* __restrict__ dst,
                                         const float* __restrict__ eattr, const int* __restrict__ rowstart,
                                         int* __restrict__ degcur, uint2* __restrict__ csr_rec,
                                         int nE, int n, int bid, int nblk) {
    const int grp = bid & 7, bin = bid >> 3, nbin = nblk >> 3;
    const int chunk = (n + 7) >> 3;
    const int lo = grp * chunk, hi = min(n, lo + chunk);
    for (int e = bin * 256 + threadIdx.x; e < nE; e += nbin * 256) {
        const int d = dst[e];
        if (d >= lo && d < hi) {
            const int p = rowstart[d] + atomicSub(&degcur[d], 1) - 1;
            uint2 rec;
            rec.x = (unsigned)src[e];
            rec.y = __builtin_bit_cast(unsigned, eattr[e]);
            csr_rec[p] = rec;
        }
    }
}

// ---- U1: deg ∪ cast(x->bf16) ∪ prep_w ----
__global__ __launch_bounds__(256)
void k_u1(const int* __restrict__ dst, int* __restrict__ deg, int nE,
          const float* __restrict__ xin, unsigned short* __restrict__ xb, long n8, int ncast,
          const float* __restrict__ Wlin, const float* __restrict__ Wmsg,
          const float* __restrict__ Wl,   const float* __restrict__ Wr,
          const float* __restrict__ Wdec, const float* __restrict__ Wfin,
          unsigned short* __restrict__ wt, int n)
{
    const int bid = blockIdx.x;
    if (bid < NBLK_SCAT) { dev_deg(dst, deg, nE, n, bid, NBLK_SCAT); return; }
    const int b = bid - NBLK_SCAT;
    if (b < ncast) {
        const long i = (long)b * 256 + threadIdx.x;
        if (i >= n8) return;
        const float4 v0 = *((const float4*)xin + i * 2);
        const float4 v1 = *((const float4*)xin + i * 2 + 1);
        unsigned o[4];
        o[0] = (unsigned)f2bf(v0.x) | ((unsigned)f2bf(v0.y) << 16);
        o[1] = (unsigned)f2bf(v0.z) | ((unsigned)f2bf(v0.w) << 16);
        o[2] = (unsigned)f2bf(v1.x) | ((unsigned)f2bf(v1.y) << 16);
        o[3] = (unsigned)f2bf(v1.z) | ((unsigned)f2bf(v1.w) << 16);
        *(uint4*)(xb + i * 8) = *(uint4*)o;
        return;
    }
    // prep_w: m: 0-2 W_lin, 3-5 W_msg(top 128), 6-8 W_l, 9-11 W_r, 12 W_dec, 13 W_fin(C=64)
    const int local = b - ncast;
    const int m = local >> 6;
    const float* src; int C = 128;
    if      (m < 3)  src = Wlin + m * 16384;
    else if (m < 6)  src = Wmsg + (m - 3) * (129 * 128);
    else if (m < 9)  src = Wl   + (m - 6) * 16384;
    else if (m < 12) src = Wr   + (m - 9) * 16384;
    else if (m == 12) src = Wdec;
    else { src = Wfin; C = 64; }
    const int elems = C * 128;
    const int e = (local & 63) * 256 + threadIdx.x;
    if (e >= elems) return;
    const int c = e >> 7, k = e & 127;
    wt[m * 16384 + e] = f2bf(src[k * C + c]);
}

// ---- U2: fill ∪ chain0 (fill blocks first to keep &7 XCD affinity) ----
__global__ __launch_bounds__(256)
void k_u2(const int* __restrict__ src, const int* __restrict__ dst,
          const float* __restrict__ eattr, const int* __restrict__ rowstart,
          int* __restrict__ degcur, uint2* __restrict__ csr_rec, int nE,
          const unsigned short* __restrict__ A, const unsigned short* __restrict__ Wt1,
          const unsigned short* __restrict__ Wtc, const float* __restrict__ b1,
          const float* __restrict__ b2, unsigned short* __restrict__ Out, int n)
{
    __shared__ __align__(16) unsigned short As1[64 * HD];
    __shared__ __align__(16) unsigned short Hs [64 * HD];
    if (blockIdx.x < NBLK_SCAT) {
        dev_fill(src, dst, eattr, rowstart, degcur, csr_rec, nE, n, blockIdx.x, NBLK_SCAT);
        return;
    }
    dev_chain<128, false>(As1, Hs, A, Wt1, Wtc, b1, b2, Out, n, blockIdx.x - NBLK_SCAT);
}

// ---- scans ----
__global__ void k_chunksum(const int* __restrict__ deg, int* __restrict__ csum, int n) {
    __shared__ int s[256];
    int t = threadIdx.x, i = blockIdx.x * 256 + t;
    s[t] = (i < n) ? deg[i] : 0;
    __syncthreads();
    for (int o = 128; o > 0; o >>= 1) { if (t < o) s[t] += s[t + o]; __syncthreads(); }
    if (t == 0) csum[blockIdx.x] = s[0];
}

__global__ void k_scanmid(const int* __restrict__ csum, int* __restrict__ cbase,
                          int* __restrict__ rowstart, int nch, int n) {
    __shared__ int s[512];
    int t = threadIdx.x;
    int v = (t < nch) ? csum[t] : 0;
    s[t] = v; __syncthreads();
    for (int off = 1; off < 512; off <<= 1) {
        int tmp = (t >= off) ? s[t - off] : 0;
        __syncthreads();
        s[t] += tmp;
        __syncthreads();
    }
    if (t < nch) cbase[t] = s[t] - v;
    if (t == nch - 1) rowstart[n] = s[t];
}

__global__ void k_scan2(const int* __restrict__ deg, const int* __restrict__ cbase,
                        int* __restrict__ rowstart, float* __restrict__ inv_deg, int n) {
    __shared__ int s[256];
    int t = threadIdx.x, i = blockIdx.x * 256 + t;
    int v = (i < n) ? deg[i] : 0;
    s[t] = v; __syncthreads();
    for (int off = 1; off < 256; off <<= 1) {
        int tmp = (t >= off) ? s[t - off] : 0;
        __syncthreads();
        s[t] += tmp;
        __syncthreads();
    }
    if (i < n) {
        rowstart[i] = cbase[blockIdx.x] + s[t] - v;
        inv_deg[i] = 1.0f / fmaxf((float)v, 1.0f);
    }
}

// agg[i] = bf16( inv_deg[i] * sum_p relu(g[src_p] + attr_p * wlast) )
// 16 lanes/node, 16B/lane, 4-edge unroll.
__global__ __launch_bounds__(256)
void k_agg(const unsigned short* __restrict__ g, const uint2* __restrict__ rec,
           const int* __restrict__ rs, const float* __restrict__ inv_deg,
           const float* __restrict__ wlast, unsigned short* __restrict__ agg, int n) {
    const int lane = threadIdx.x & 15;
    const int node = blockIdx.x * 16 + (threadIdx.x >> 4);
    if (node >= n) return;
    const int c0 = lane * 8;
    const float4 wla = *(const float4*)(wlast + c0);
    const float4 wlb = *(const float4*)(wlast + c0 + 4);
    const int p0 = rs[node], p1 = rs[node + 1];
    float a0=0,a1=0,a2=0,a3=0,a4=0,a5=0,a6=0,a7=0;
    int p = p0;
    for (; p + 4 <= p1; p += 4) {
        uint2 r[4];
#pragma unroll
        for (int u = 0; u < 4; ++u) r[u] = rec[p + u];
        uint4 G[4];
#pragma unroll
        for (int u = 0; u < 4; ++u) G[u] = *(const uint4*)(g + (long)r[u].x * HD + c0);
#pragma unroll
        for (int u = 0; u < 4; ++u) {
            const float e = __builtin_bit_cast(float, r[u].y);
            a0 += fmaxf(fmaf(e, wla.x, bflo(G[u].x)), 0.f);
            a1 += fmaxf(fmaf(e, wla.y, bfhi(G[u].x)), 0.f);
            a2 += fmaxf(fmaf(e, wla.z, bflo(G[u].y)), 0.f);
            a3 += fmaxf(fmaf(e, wla.w, bfhi(G[u].y)), 0.f);
            a4 += fmaxf(fmaf(e, wlb.x, bflo(G[u].z)), 0.f);
            a5 += fmaxf(fmaf(e, wlb.y, bfhi(G[u].z)), 0.f);
            a6 += fmaxf(fmaf(e, wlb.z, bflo(G[u].w)), 0.f);
            a7 += fmaxf(fmaf(e, wlb.w, bfhi(G[u].w)), 0.f);
        }
    }
    for (; p < p1; ++p) {
        const uint2 r0 = rec[p];
        const float e0 = __builtin_bit_cast(float, r0.y);
        const uint4 G0 = *(const uint4*)(g + (long)r0.x * HD + c0);
        a0 += fmaxf(fmaf(e0, wla.x, bflo(G0.x)), 0.f);
        a1 += fmaxf(fmaf(e0, wla.y, bfhi(G0.x)), 0.f);
        a2 += fmaxf(fmaf(e0, wla.z, bflo(G0.y)), 0.f);
        a3 += fmaxf(fmaf(e0, wla.w, bfhi(G0.y)), 0.f);
        a4 += fmaxf(fmaf(e0, wlb.x, bflo(G0.z)), 0.f);
        a5 += fmaxf(fmaf(e0, wlb.y, bfhi(G0.z)), 0.f);
        a6 += fmaxf(fmaf(e0, wlb.z, bflo(G0.w)), 0.f);
        a7 += fmaxf(fmaf(e0, wlb.w, bfhi(G0.w)), 0.f);
    }
    const float id = inv_deg[node];
    uint4 o;
    o.x = (unsigned)f2bf(a0 * id) | ((unsigned)f2bf(a1 * id) << 16);
    o.y = (unsigned)f2bf(a2 * id) | ((unsigned)f2bf(a3 * id) << 16);
    o.z = (unsigned)f2bf(a4 * id) | ((unsigned)f2bf(a5 * id) << 16);
    o.w = (unsigned)f2bf(a6 * id) | ((unsigned)f2bf(a7 * id) << 16);
    *(uint4*)(agg + (long)node * HD + c0) = o;
}

extern "C" void kernel_launch(void* const* d_in, const int* in_sizes, int n_in,
                              void* d_out, int out_size, void* d_ws, size_t ws_size,
                              hipStream_t stream)
{
    const float* x     = (const float*)d_in[0];
    const float* eattr = (const float*)d_in[1];
    const float* W_lin = (const float*)d_in[2];
    const float* b_lin = (const float*)d_in[3];
    const float* W_msg = (const float*)d_in[4];
    const float* b_msg = (const float*)d_in[5];
    const float* W_l   = (const float*)d_in[6];
    const float* b_l   = (const float*)d_in[7];
    const float* W_r   = (const float*)d_in[8];
    const float* W_dec = (const float*)d_in[9];
    const float* b_dec = (const float*)d_in[10];
    const float* W_fin = (const float*)d_in[11];
    const float* b_fin = (const float*)d_in[12];
    const int*   ei    = (const int*)d_in[13];

    const int N = in_sizes[0] / HD;   // 100000
    const int E = in_sizes[1];        // 600000
    const int* srcv = ei;
    const int* dstv = ei + E;

    char* wsb = (char*)d_ws;
    size_t off = 0;
    auto carve = [&](size_t bytes) -> void* {
        void* p = wsb + off;
        off += (bytes + 255) & ~(size_t)255;
        return p;
    };
    unsigned short* xb = (unsigned short*)carve((size_t)N * HD * 2);
    unsigned short* t1 = (unsigned short*)carve((size_t)N * HD * 2);
    unsigned short* t2 = (unsigned short*)carve((size_t)N * HD * 2);
    unsigned short* t3 = (unsigned short*)carve((size_t)N * HD * 2);
    unsigned short* wt = (unsigned short*)carve((size_t)14 * 16384 * 2);
    uint2* csr_rec  = (uint2*)carve((size_t)E * 8);
    int*   rowstart = (int*)carve((size_t)(N + 1) * 4);
    int*   deg      = (int*)carve((size_t)N * 4);
    float* inv_deg  = (float*)carve((size_t)N * 4);
    const int NCH = (N + 255) / 256;
    int* csum  = (int*)carve((size_t)NCH * 4);
    int* cbase = (int*)carve((size_t)NCH * 4);

    if (off > ws_size) {
        hipMemsetAsync(d_out, 0, (size_t)out_size * 4, stream);
        return;
    }

    hipMemsetAsync(deg, 0, (size_t)N * 4, stream);

    auto WT = [&](int m) { return wt + (size_t)m * 16384; };
    const int NB64 = (N + 63) / 64;
    const int GAGG = (N + 15) / 16;
    const long n8 = (long)N * HD / 8;
    const int ncast = (int)((n8 + 255) / 256);

    // U1: deg ∪ cast ∪ prep_w
    k_u1<<<NBLK_SCAT + ncast + 14 * 64, 256, 0, stream>>>(
        dstv, deg, E, x, xb, n8, ncast, W_lin, W_msg, W_l, W_r, W_dec, W_fin, wt, N);
    k_chunksum<<<NCH, 256, 0, stream>>>(deg, csum, N);
    k_scanmid<<<1, 512, 0, stream>>>(csum, cbase, rowstart, NCH, N);
    k_scan2<<<NCH, 256, 0, stream>>>(deg, cbase, rowstart, inv_deg, N);

    // U2: fill ∪ chain0 (xb -> g0 in t2)
    k_u2<<<NBLK_SCAT + NB64, 256, 0, stream>>>(
        srcv, dstv, eattr, rowstart, deg, csr_rec, E,
        xb, WT(0), WT(3), b_lin, b_msg, t2, N);

    auto wlast = [&](int l) { return W_msg + (size_t)l * (HD + 1) * HD + (size_t)HD * HD; };

    // Alias-free rotation: x path xb -> t3 -> xb ; g -> t2 ; agg -> t1.
    // agg0: g0(t2) -> t1
    k_agg<<<GAGG, 256, 0, stream>>>(t2, csr_rec, rowstart, inv_deg, wlast(0), t1, N);
    // dualchain l0->l1: Agg=t1, X=xb -> x1=t3, g1=t2 (g0 dead)
    k_dualchain<<<NB64, 512, 0, stream>>>(
        t1, xb, WT(6), WT(9), b_l, WT(1), b_lin + HD, WT(4), b_msg + HD, t3, t2, N);
    // agg1: g1(t2) -> t1 (agg0 dead)
    k_agg<<<GAGG, 256, 0, stream>>>(t2, csr_rec, rowstart, inv_deg, wlast(1), t1, N);
    // dualchain l1->l2: Agg=t1, X=t3 -> x2=xb (xb dead), g2=t2 (g1 dead)
    k_dualchain<<<NB64, 512, 0, stream>>>(
        t1, t3, WT(7), WT(10), b_l + HD, WT(2), b_lin + 2 * HD, WT(5), b_msg + 2 * HD, xb, t2, N);
    // agg2: g2(t2) -> t1 (agg1 dead)
    k_agg<<<GAGG, 256, 0, stream>>>(t2, csr_rec, rowstart, inv_deg, wlast(2), t1, N);
    // dual2 + decoder: Agg=t1, X=xb -> d_out
    k_dualdec<<<NB64, 512, 0, stream>>>(t1, xb, WT(8), WT(11), b_l + 2 * HD,
                                        WT(12), b_dec, WT(13), b_fin, (float*)d_out, N);
}

// Round 16
// 319.220 us; speedup vs baseline: 1.1737x; 1.1737x over previous
//
#include <hip/hip_runtime.h>

using short8 = __attribute__((ext_vector_type(8))) short;
using f32x4  = __attribute__((ext_vector_type(4))) float;

constexpr int HD = 128;
constexpr int NBLK_SCAT = 2048;   // scatter (deg/fill) blocks: 8 XCD groups x 256

__device__ __forceinline__ unsigned short f2bf(float f) {
    unsigned u = __builtin_bit_cast(unsigned, f);
    u += 0x7fffu + ((u >> 16) & 1u);          // round-to-nearest-even
    return (unsigned short)(u >> 16);
}
__device__ __forceinline__ float bflo(unsigned u) { return __builtin_bit_cast(float, u << 16); }
__device__ __forceinline__ float bfhi(unsigned u) { return __builtin_bit_cast(float, u & 0xffff0000u); }

__device__ __forceinline__ short8 ldg8(const unsigned short* p) {
    return *reinterpret_cast<const short8*>(p);   // 16B contiguous, aligned
}

// ---------------------------------------------------------------------------
// Chain GEMM body: Out = (relu(A @ Wt1 + b1)) @ Wtc + b2. 64 rows x 128 cols,
// A via global_load_lds with pre-swizzled source (m173); h in swizzled LDS.
// ---------------------------------------------------------------------------
template<int NC2, bool F32OUT>
__device__ __forceinline__ void dev_chain(unsigned short* As1, unsigned short* Hs,
    const unsigned short* __restrict__ A, const unsigned short* __restrict__ Wt1,
    const unsigned short* __restrict__ Wtc, const float* __restrict__ b1,
    const float* __restrict__ b2, void* __restrict__ Out, int nrows, int bid)
{
    const int tid  = threadIdx.x;
    const int lane = tid & 63, wave = tid >> 6;
    const int lr = lane & 15, lg = lane >> 4;
    const int row0 = bid * 64;

#pragma unroll
    for (int it = 0; it < 4; ++it) {
        const int q   = wave * 4 + it;
        const int c   = q * 64 + lane;
        const int row = c >> 4, cw = c & 15;
        int grow = row0 + row; grow = grow < nrows ? grow : nrows - 1;
        const int gco = (cw ^ (row & 7)) << 3;
        __builtin_amdgcn_global_load_lds((const unsigned int*)(A + (long)grow * HD + gco),
                                         (unsigned int*)&As1[q * 512], 16, 0, 0);
    }

    const int cb1 = wave * 32;
    short8 bf1[2][4];
#pragma unroll
    for (int ct = 0; ct < 2; ++ct) {
        const unsigned short* bp = Wt1 + (long)(cb1 + ct * 16 + lr) * HD + lg * 8;
#pragma unroll
        for (int kt = 0; kt < 4; ++kt) bf1[ct][kt] = ldg8(bp + kt * 32);
    }
    constexpr int CT2 = NC2 / 64;
    const int cb2 = wave * (NC2 / 4);
    short8 bfc[CT2][4];
#pragma unroll
    for (int ct = 0; ct < CT2; ++ct) {
        const unsigned short* bp = Wtc + (long)(cb2 + ct * 16 + lr) * HD + lg * 8;
#pragma unroll
        for (int kt = 0; kt < 4; ++kt) bfc[ct][kt] = ldg8(bp + kt * 32);
    }

    __syncthreads();

    f32x4 acc[4][2] = {};
#pragma unroll
    for (int kt = 0; kt < 4; ++kt) {
        short8 af[4];
#pragma unroll
        for (int rt = 0; rt < 4; ++rt)
            af[rt] = *reinterpret_cast<const short8*>(
                &As1[(rt * 16 + lr) * HD + (((kt * 4 + lg) ^ (lr & 7)) << 3)]);
#pragma unroll
        for (int rt = 0; rt < 4; ++rt)
#pragma unroll
            for (int ct = 0; ct < 2; ++ct)
                acc[rt][ct] = __builtin_amdgcn_mfma_f32_16x16x32_bf16(af[rt], bf1[ct][kt], acc[rt][ct], 0, 0, 0);
    }

    const float bv1[2] = { b1[cb1 + lr], b1[cb1 + 16 + lr] };
#pragma unroll
    for (int rt = 0; rt < 4; ++rt)
#pragma unroll
        for (int ct = 0; ct < 2; ++ct) {
            const int cc = cb1 + ct * 16 + lr;
#pragma unroll
            for (int i = 0; i < 4; ++i) {
                const int row = rt * 16 + lg * 4 + i;
                const float v = fmaxf(acc[rt][ct][i] + bv1[ct], 0.f);
                Hs[row * HD + ((((cc >> 3) ^ (row & 7)) << 3) | (cc & 7))] = f2bf(v);
            }
        }
    __syncthreads();

    f32x4 acc2[4][CT2] = {};
#pragma unroll
    for (int kt = 0; kt < 4; ++kt) {
        short8 ah[4];
#pragma unroll
        for (int rt = 0; rt < 4; ++rt)
            ah[rt] = *reinterpret_cast<const short8*>(
                &Hs[(rt * 16 + lr) * HD + (((kt * 4 + lg) ^ (lr & 7)) << 3)]);
#pragma unroll
        for (int rt = 0; rt < 4; ++rt)
#pragma unroll
            for (int ct = 0; ct < CT2; ++ct)
                acc2[rt][ct] = __builtin_amdgcn_mfma_f32_16x16x32_bf16(ah[rt], bfc[ct][kt], acc2[rt][ct], 0, 0, 0);
    }
    float bv2[CT2];
#pragma unroll
    for (int ct = 0; ct < CT2; ++ct) bv2[ct] = b2[cb2 + ct * 16 + lr];
#pragma unroll
    for (int rt = 0; rt < 4; ++rt)
#pragma unroll
        for (int ct = 0; ct < CT2; ++ct) {
            const int cc = cb2 + ct * 16 + lr;
#pragma unroll
            for (int i = 0; i < 4; ++i) {
                const int r = row0 + rt * 16 + lg * 4 + i;
                if (r < nrows) {
                    const float v = acc2[rt][ct][i] + bv2[ct];
                    if constexpr (F32OUT) ((float*)Out)[(long)r * NC2 + cc] = v;
                    else ((unsigned short*)Out)[(long)r * NC2 + cc] = f2bf(v);
                }
            }
        }
}

// ---------------------------------------------------------------------------
// Merged dual + next-layer chain (64-row blocks, 3 LDS buffers = 48KB):
//   phase1: x' = relu(Ag@WtL + Xs@WtR + bl) -> Ts (LDS only; NO global store
//           before the barriers -- vmcnt drain at __syncthreads would stall)
//   phase2: h  = relu(Ts@Wt1 + b1) -> Ag
//   phase3: g  = Ag@Wtc + b2 -> Gout global
//   tail : deferred coalesced x' write-out Ts -> Xout (uint4 unswizzle copy;
//          Ts untouched since phase1, barriers 2/3 already ordered it)
// Caller guarantees Xout/Gout do not alias Agg/X.
// ---------------------------------------------------------------------------
__global__ __launch_bounds__(256)
void k_dualchain(const unsigned short* __restrict__ Agg, const unsigned short* __restrict__ X,
                 const unsigned short* __restrict__ WtL, const unsigned short* __restrict__ WtR,
                 const float* __restrict__ bl_,
                 const unsigned short* __restrict__ Wt1, const float* __restrict__ b1,
                 const unsigned short* __restrict__ Wtc, const float* __restrict__ b2,
                 unsigned short* __restrict__ Xout, unsigned short* __restrict__ Gout, int n)
{
    __shared__ __align__(16) unsigned short Ag[64 * HD];
    __shared__ __align__(16) unsigned short Xs[64 * HD];
    __shared__ __align__(16) unsigned short Ts[64 * HD];

    const int tid  = threadIdx.x;
    const int lane = tid & 63, wave = tid >> 6;
    const int lr = lane & 15, lg = lane >> 4;
    const int row0 = blockIdx.x * 64;

#pragma unroll
    for (int it = 0; it < 4; ++it) {
        const int q   = wave * 4 + it;
        const int c   = q * 64 + lane;
        const int row = c >> 4, cw = c & 15;
        int grow = row0 + row; grow = grow < n ? grow : n - 1;
        const int gco = (cw ^ (row & 7)) << 3;
        __builtin_amdgcn_global_load_lds((const unsigned int*)(Agg + (long)grow * HD + gco),
                                         (unsigned int*)&Ag[q * 512], 16, 0, 0);
        __builtin_amdgcn_global_load_lds((const unsigned int*)(X + (long)grow * HD + gco),
                                         (unsigned int*)&Xs[q * 512], 16, 0, 0);
    }

    const int cb = wave * 32;
    short8 bl[2][4], br[2][4];
#pragma unroll
    for (int ct = 0; ct < 2; ++ct) {
        const unsigned short* pl = WtL + (long)(cb + ct * 16 + lr) * HD + lg * 8;
        const unsigned short* pr = WtR + (long)(cb + ct * 16 + lr) * HD + lg * 8;
#pragma unroll
        for (int kt = 0; kt < 4; ++kt) { bl[ct][kt] = ldg8(pl + kt * 32); br[ct][kt] = ldg8(pr + kt * 32); }
    }
    __syncthreads();   // (1) DMA + weights drained

    // phase 1: x' = relu(Ag@WtL + Xs@WtR + bl) -> Ts (LDS only)
    {
        f32x4 acc[4][2] = {};
#pragma unroll
        for (int kt = 0; kt < 4; ++kt) {
            short8 aa[4], ax[4];
#pragma unroll
            for (int rt = 0; rt < 4; ++rt) {
                const int base = (rt * 16 + lr) * HD + (((kt * 4 + lg) ^ (lr & 7)) << 3);
                aa[rt] = *reinterpret_cast<const short8*>(&Ag[base]);
                ax[rt] = *reinterpret_cast<const short8*>(&Xs[base]);
            }
#pragma unroll
            for (int rt = 0; rt < 4; ++rt)
#pragma unroll
                for (int ct = 0; ct < 2; ++ct) {
                    acc[rt][ct] = __builtin_amdgcn_mfma_f32_16x16x32_bf16(aa[rt], bl[ct][kt], acc[rt][ct], 0, 0, 0);
                    acc[rt][ct] = __builtin_amdgcn_mfma_f32_16x16x32_bf16(ax[rt], br[ct][kt], acc[rt][ct], 0, 0, 0);
                }
        }
        const float bv[2] = { bl_[cb + lr], bl_[cb + 16 + lr] };
#pragma unroll
        for (int rt = 0; rt < 4; ++rt)
#pragma unroll
            for (int ct = 0; ct < 2; ++ct) {
                const int cc = cb + ct * 16 + lr;
#pragma unroll
                for (int i = 0; i < 4; ++i) {
                    const int row = rt * 16 + lg * 4 + i;
                    const float v = fmaxf(acc[rt][ct][i] + bv[ct], 0.f);
                    Ts[row * HD + ((((cc >> 3) ^ (row & 7)) << 3) | (cc & 7))] = f2bf(v);
                }
            }
    }
    __syncthreads();   // (2) Ts visible; all Ag/Xs reads done (drains only weight loads)

    // phase 2: h = relu(Ts@Wt1 + b1) -> Ag
    {
        short8 b1f[2][4];
#pragma unroll
        for (int ct = 0; ct < 2; ++ct) {
            const unsigned short* bp = Wt1 + (long)(cb + ct * 16 + lr) * HD + lg * 8;
#pragma unroll
            for (int kt = 0; kt < 4; ++kt) b1f[ct][kt] = ldg8(bp + kt * 32);
        }
        f32x4 a2[4][2] = {};
#pragma unroll
        for (int kt = 0; kt < 4; ++kt) {
            short8 ah[4];
#pragma unroll
            for (int rt = 0; rt < 4; ++rt)
                ah[rt] = *reinterpret_cast<const short8*>(
                    &Ts[(rt * 16 + lr) * HD + (((kt * 4 + lg) ^ (lr & 7)) << 3)]);
#pragma unroll
            for (int rt = 0; rt < 4; ++rt)
#pragma unroll
                for (int ct = 0; ct < 2; ++ct)
                    a2[rt][ct] = __builtin_amdgcn_mfma_f32_16x16x32_bf16(ah[rt], b1f[ct][kt], a2[rt][ct], 0, 0, 0);
        }
        // issue phase-3 weights (hide under epilogue + barrier)
        short8 bcf[2][4];
#pragma unroll
        for (int ct = 0; ct < 2; ++ct) {
            const unsigned short* bp = Wtc + (long)(cb + ct * 16 + lr) * HD + lg * 8;
#pragma unroll
            for (int kt = 0; kt < 4; ++kt) bcf[ct][kt] = ldg8(bp + kt * 32);
        }
        const float bv[2] = { b1[cb + lr], b1[cb + 16 + lr] };
#pragma unroll
        for (int rt = 0; rt < 4; ++rt)
#pragma unroll
            for (int ct = 0; ct < 2; ++ct) {
                const int cc = cb + ct * 16 + lr;
#pragma unroll
                for (int i = 0; i < 4; ++i) {
                    const int row = rt * 16 + lg * 4 + i;
                    const float v = fmaxf(a2[rt][ct][i] + bv[ct], 0.f);
                    Ag[row * HD + ((((cc >> 3) ^ (row & 7)) << 3) | (cc & 7))] = f2bf(v);
                }
            }
        __syncthreads();   // (3) h visible

        // phase 3: g = Ag@Wtc + b2 -> Gout
        f32x4 a3[4][2] = {};
#pragma unroll
        for (int kt = 0; kt < 4; ++kt) {
            short8 ah[4];
#pragma unroll
            for (int rt = 0; rt < 4; ++rt)
                ah[rt] = *reinterpret_cast<const short8*>(
                    &Ag[(rt * 16 + lr) * HD + (((kt * 4 + lg) ^ (lr & 7)) << 3)]);
#pragma unroll
            for (int rt = 0; rt < 4; ++rt)
#pragma unroll
                for (int ct = 0; ct < 2; ++ct)
                    a3[rt][ct] = __builtin_amdgcn_mfma_f32_16x16x32_bf16(ah[rt], bcf[ct][kt], a3[rt][ct], 0, 0, 0);
        }
        const float bv2[2] = { b2[cb + lr], b2[cb + 16 + lr] };
#pragma unroll
        for (int rt = 0; rt < 4; ++rt)
#pragma unroll
            for (int ct = 0; ct < 2; ++ct) {
                const int cc = cb + ct * 16 + lr;
#pragma unroll
                for (int i = 0; i < 4; ++i) {
                    const int r = row0 + rt * 16 + lg * 4 + i;
                    if (r < n) Gout[(long)r * HD + cc] = f2bf(a3[rt][ct][i] + bv2[ct]);
                }
            }
    }

    // ---- deferred coalesced x' write-out: Ts -> Xout (no barrier needed:
    // Ts untouched since phase 1; barriers 2/3 ordered all its writes) ----
#pragma unroll
    for (int k = 0; k < 4; ++k) {
        const int c   = tid + k * 256;        // 16B chunk id 0..1023
        const int row = c >> 4, cw = c & 15;
        const int r = row0 + row;
        if (r < n) {
            const uint4 v = *reinterpret_cast<const uint4*>(
                &Ts[row * HD + ((cw ^ (row & 7)) << 3)]);
            *reinterpret_cast<uint4*>(Xout + (long)r * HD + cw * 8) = v;
        }
    }
}

// ---------------------------------------------------------------------------
// Merged dual + decoder (64-row blocks, 3 LDS buffers):
//   phase1: x3 = relu(Ag@WtL + Xs@WtR + bl) -> Ts
//   phase2: emb = relu(Ts@Wdec + bdec) -> Ag
//   phase3: logits = Ag@Wfin + bfin -> f32 out
// ---------------------------------------------------------------------------
__global__ __launch_bounds__(256)
void k_dualdec(const unsigned short* __restrict__ Agg, const unsigned short* __restrict__ X,
               const unsigned short* __restrict__ WtL, const unsigned short* __restrict__ WtR,
               const float* __restrict__ bl_, const unsigned short* __restrict__ Wdec,
               const float* __restrict__ bdec, const unsigned short* __restrict__ Wfin,
               const float* __restrict__ bfin, float* __restrict__ Out, int n)
{
    __shared__ __align__(16) unsigned short Ag[64 * HD];
    __shared__ __align__(16) unsigned short Xs[64 * HD];
    __shared__ __align__(16) unsigned short Ts[64 * HD];

    const int tid  = threadIdx.x;
    const int lane = tid & 63, wave = tid >> 6;
    const int lr = lane & 15, lg = lane >> 4;
    const int row0 = blockIdx.x * 64;

#pragma unroll
    for (int it = 0; it < 4; ++it) {
        const int q   = wave * 4 + it;
        const int c   = q * 64 + lane;
        const int row = c >> 4, cw = c & 15;
        int grow = row0 + row; grow = grow < n ? grow : n - 1;
        const int gco = (cw ^ (row & 7)) << 3;
        __builtin_amdgcn_global_load_lds((const unsigned int*)(Agg + (long)grow * HD + gco),
                                         (unsigned int*)&Ag[q * 512], 16, 0, 0);
        __builtin_amdgcn_global_load_lds((const unsigned int*)(X + (long)grow * HD + gco),
                                         (unsigned int*)&Xs[q * 512], 16, 0, 0);
    }

    const int cb = wave * 32;
    short8 bl[2][4], br[2][4];
#pragma unroll
    for (int ct = 0; ct < 2; ++ct) {
        const unsigned short* pl = WtL + (long)(cb + ct * 16 + lr) * HD + lg * 8;
        const unsigned short* pr = WtR + (long)(cb + ct * 16 + lr) * HD + lg * 8;
#pragma unroll
        for (int kt = 0; kt < 4; ++kt) { bl[ct][kt] = ldg8(pl + kt * 32); br[ct][kt] = ldg8(pr + kt * 32); }
    }
    __syncthreads();   // (1)

    // phase 1: x3 = relu(Ag@WtL + Xs@WtR + bl) -> Ts (swizzled)
    {
        f32x4 acc[4][2] = {};
#pragma unroll
        for (int kt = 0; kt < 4; ++kt) {
            short8 aa[4], ax[4];
#pragma unroll
            for (int rt = 0; rt < 4; ++rt) {
                const int base = (rt * 16 + lr) * HD + (((kt * 4 + lg) ^ (lr & 7)) << 3);
                aa[rt] = *reinterpret_cast<const short8*>(&Ag[base]);
                ax[rt] = *reinterpret_cast<const short8*>(&Xs[base]);
            }
#pragma unroll
            for (int rt = 0; rt < 4; ++rt)
#pragma unroll
                for (int ct = 0; ct < 2; ++ct) {
                    acc[rt][ct] = __builtin_amdgcn_mfma_f32_16x16x32_bf16(aa[rt], bl[ct][kt], acc[rt][ct], 0, 0, 0);
                    acc[rt][ct] = __builtin_amdgcn_mfma_f32_16x16x32_bf16(ax[rt], br[ct][kt], acc[rt][ct], 0, 0, 0);
                }
        }
        const float bv[2] = { bl_[cb + lr], bl_[cb + 16 + lr] };
#pragma unroll
        for (int rt = 0; rt < 4; ++rt)
#pragma unroll
            for (int ct = 0; ct < 2; ++ct) {
                const int cc = cb + ct * 16 + lr;
#pragma unroll
                for (int i = 0; i < 4; ++i) {
                    const int row = rt * 16 + lg * 4 + i;
                    const float v = fmaxf(acc[rt][ct][i] + bv[ct], 0.f);
                    Ts[row * HD + ((((cc >> 3) ^ (row & 7)) << 3) | (cc & 7))] = f2bf(v);
                }
            }
    }
    __syncthreads();   // (2)

    // phase 2: emb = relu(Ts@Wdec + bdec) -> Ag (Ag reads all done)
    {
        short8 bd[2][4];
#pragma unroll
        for (int ct = 0; ct < 2; ++ct) {
            const unsigned short* bp = Wdec + (long)(cb + ct * 16 + lr) * HD + lg * 8;
#pragma unroll
            for (int kt = 0; kt < 4; ++kt) bd[ct][kt] = ldg8(bp + kt * 32);
        }
        f32x4 a2[4][2] = {};
#pragma unroll
        for (int kt = 0; kt < 4; ++kt) {
            short8 ah[4];
#pragma unroll
            for (int rt = 0; rt < 4; ++rt)
                ah[rt] = *reinterpret_cast<const short8*>(
                    &Ts[(rt * 16 + lr) * HD + (((kt * 4 + lg) ^ (lr & 7)) << 3)]);
#pragma unroll
            for (int rt = 0; rt < 4; ++rt)
#pragma unroll
                for (int ct = 0; ct < 2; ++ct)
                    a2[rt][ct] = __builtin_amdgcn_mfma_f32_16x16x32_bf16(ah[rt], bd[ct][kt], a2[rt][ct], 0, 0, 0);
        }
        const int cbf = wave * 16;
        short8 bfn[4];
#pragma unroll
        for (int kt = 0; kt < 4; ++kt)
            bfn[kt] = ldg8(Wfin + (long)(cbf + lr) * HD + lg * 8 + kt * 32);
        const float bv[2] = { bdec[cb + lr], bdec[cb + 16 + lr] };
#pragma unroll
        for (int rt = 0; rt < 4; ++rt)
#pragma unroll
            for (int ct = 0; ct < 2; ++ct) {
                const int cc = cb + ct * 16 + lr;
#pragma unroll
                for (int i = 0; i < 4; ++i) {
                    const int row = rt * 16 + lg * 4 + i;
                    const float v = fmaxf(a2[rt][ct][i] + bv[ct], 0.f);
                    Ag[row * HD + ((((cc >> 3) ^ (row & 7)) << 3) | (cc & 7))] = f2bf(v);
                }
            }
        __syncthreads();   // (3)

        // phase 3: logits = Ag@Wfin + bfin -> f32 (64 cols; wave covers 16)
        f32x4 a3[4] = {};
#pragma unroll
        for (int kt = 0; kt < 4; ++kt) {
            short8 ah[4];
#pragma unroll
            for (int rt = 0; rt < 4; ++rt)
                ah[rt] = *reinterpret_cast<const short8*>(
                    &Ag[(rt * 16 + lr) * HD + (((kt * 4 + lg) ^ (lr & 7)) << 3)]);
#pragma unroll
            for (int rt = 0; rt < 4; ++rt)
                a3[rt] = __builtin_amdgcn_mfma_f32_16x16x32_bf16(ah[rt], bfn[kt], a3[rt], 0, 0, 0);
        }
        const float bvf = bfin[cbf + lr];
#pragma unroll
        for (int rt = 0; rt < 4; ++rt)
#pragma unroll
            for (int i = 0; i < 4; ++i) {
                const int r = row0 + rt * 16 + lg * 4 + i;
                if (r < n) Out[(long)r * 64 + cbf + lr] = a3[rt][i] + bvf;
            }
    }
}

// ---- scatter bodies (XCD-affine: 8 node-chunks, group = bid&7) ----
__device__ __forceinline__ void dev_deg(const int* __restrict__ dst, int* __restrict__ deg,
                                        int nE, int n, int bid, int nblk) {
    const int grp = bid & 7, bin = bid >> 3, nbin = nblk >> 3;
    const int chunk = (n + 7) >> 3;
    const int lo = grp * chunk, hi = min(n, lo + chunk);
    for (int e = bin * 256 + threadIdx.x; e < nE; e += nbin * 256) {
        const int d = dst[e];
        if (d >= lo && d < hi) atomicAdd(&deg[d], 1);
    }
}

__device__ __forceinline__ void dev_fill(const int* __restrict__ src, const int* __restrict__ dst,
                                         const float* __restrict__ eattr, const int* __restrict__ rowstart,
                                         int* __restrict__ degcur, uint2* __restrict__ csr_rec,
                                         int nE, int n, int bid, int nblk) {
    const int grp = bid & 7, bin = bid >> 3, nbin = nblk >> 3;
    const int chunk = (n + 7) >> 3;
    const int lo = grp * chunk, hi = min(n, lo + chunk);
    for (int e = bin * 256 + threadIdx.x; e < nE; e += nbin * 256) {
        const int d = dst[e];
        if (d >= lo && d < hi) {
            const int p = rowstart[d] + atomicSub(&degcur[d], 1) - 1;
            uint2 rec;
            rec.x = (unsigned)src[e];
            rec.y = __builtin_bit_cast(unsigned, eattr[e]);
            csr_rec[p] = rec;
        }
    }
}

// ---- U1: deg ∪ cast(x->bf16) ∪ prep_w ----
__global__ __launch_bounds__(256)
void k_u1(const int* __restrict__ dst, int* __restrict__ deg, int nE,
          const float* __restrict__ xin, unsigned short* __restrict__ xb, long n8, int ncast,
          const float* __restrict__ Wlin, const float* __restrict__ Wmsg,
          const float* __restrict__ Wl,   const float* __restrict__ Wr,
          const float* __restrict__ Wdec, const float* __restrict__ Wfin,
          unsigned short* __restrict__ wt, int n)
{
    const int bid = blockIdx.x;
    if (bid < NBLK_SCAT) { dev_deg(dst, deg, nE, n, bid, NBLK_SCAT); return; }
    const int b = bid - NBLK_SCAT;
    if (b < ncast) {
        const long i = (long)b * 256 + threadIdx.x;
        if (i >= n8) return;
        const float4 v0 = *((const float4*)xin + i * 2);
        const float4 v1 = *((const float4*)xin + i * 2 + 1);
        unsigned o[4];
        o[0] = (unsigned)f2bf(v0.x) | ((unsigned)f2bf(v0.y) << 16);
        o[1] = (unsigned)f2bf(v0.z) | ((unsigned)f2bf(v0.w) << 16);
        o[2] = (unsigned)f2bf(v1.x) | ((unsigned)f2bf(v1.y) << 16);
        o[3] = (unsigned)f2bf(v1.z) | ((unsigned)f2bf(v1.w) << 16);
        *(uint4*)(xb + i * 8) = *(uint4*)o;
        return;
    }
    // prep_w: m: 0-2 W_lin, 3-5 W_msg(top 128), 6-8 W_l, 9-11 W_r, 12 W_dec, 13 W_fin(C=64)
    const int local = b - ncast;
    const int m = local >> 6;
    const float* src; int C = 128;
    if      (m < 3)  src = Wlin + m * 16384;
    else if (m < 6)  src = Wmsg + (m - 3) * (129 * 128);
    else if (m < 9)  src = Wl   + (m - 6) * 16384;
    else if (m < 12) src = Wr   + (m - 9) * 16384;
    else if (m == 12) src = Wdec;
    else { src = Wfin; C = 64; }
    const int elems = C * 128;
    const int e = (local & 63) * 256 + threadIdx.x;
    if (e >= elems) return;
    const int c = e >> 7, k = e & 127;
    wt[m * 16384 + e] = f2bf(src[k * C + c]);
}

// ---- U2: fill ∪ chain0 (fill blocks first to keep &7 XCD affinity) ----
__global__ __launch_bounds__(256)
void k_u2(const int* __restrict__ src, const int* __restrict__ dst,
          const float* __restrict__ eattr, const int* __restrict__ rowstart,
          int* __restrict__ degcur, uint2* __restrict__ csr_rec, int nE,
          const unsigned short* __restrict__ A, const unsigned short* __restrict__ Wt1,
          const unsigned short* __restrict__ Wtc, const float* __restrict__ b1,
          const float* __restrict__ b2, unsigned short* __restrict__ Out, int n)
{
    __shared__ __align__(16) unsigned short As1[64 * HD];
    __shared__ __align__(16) unsigned short Hs [64 * HD];
    if (blockIdx.x < NBLK_SCAT) {
        dev_fill(src, dst, eattr, rowstart, degcur, csr_rec, nE, n, blockIdx.x, NBLK_SCAT);
        return;
    }
    dev_chain<128, false>(As1, Hs, A, Wt1, Wtc, b1, b2, Out, n, blockIdx.x - NBLK_SCAT);
}

// ---- scans ----
__global__ void k_chunksum(const int* __restrict__ deg, int* __restrict__ csum, int n) {
    __shared__ int s[256];
    int t = threadIdx.x, i = blockIdx.x * 256 + t;
    s[t] = (i < n) ? deg[i] : 0;
    __syncthreads();
    for (int o = 128; o > 0; o >>= 1) { if (t < o) s[t] += s[t + o]; __syncthreads(); }
    if (t == 0) csum[blockIdx.x] = s[0];
}

__global__ void k_scanmid(const int* __restrict__ csum, int* __restrict__ cbase,
                          int* __restrict__ rowstart, int nch, int n) {
    __shared__ int s[512];
    int t = threadIdx.x;
    int v = (t < nch) ? csum[t] : 0;
    s[t] = v; __syncthreads();
    for (int off = 1; off < 512; off <<= 1) {
        int tmp = (t >= off) ? s[t - off] : 0;
        __syncthreads();
        s[t] += tmp;
        __syncthreads();
    }
    if (t < nch) cbase[t] = s[t] - v;
    if (t == nch - 1) rowstart[n] = s[t];
}

__global__ void k_scan2(const int* __restrict__ deg, const int* __restrict__ cbase,
                        int* __restrict__ rowstart, float* __restrict__ inv_deg, int n) {
    __shared__ int s[256];
    int t = threadIdx.x, i = blockIdx.x * 256 + t;
    int v = (i < n) ? deg[i] : 0;
    s[t] = v; __syncthreads();
    for (int off = 1; off < 256; off <<= 1) {
        int tmp = (t >= off) ? s[t - off] : 0;
        __syncthreads();
        s[t] += tmp;
        __syncthreads();
    }
    if (i < n) {
        rowstart[i] = cbase[blockIdx.x] + s[t] - v;
        inv_deg[i] = 1.0f / fmaxf((float)v, 1.0f);
    }
}

// agg[i] = bf16( inv_deg[i] * sum_p relu(g[src_p] + attr_p * wlast) )
// 16 lanes/node, 16B/lane, 4-edge unroll.
__global__ __launch_bounds__(256)
void k_agg(const unsigned short* __restrict__ g, const uint2* __restrict__ rec,
           const int* __restrict__ rs, const float* __restrict__ inv_deg,
           const float* __restrict__ wlast, unsigned short* __restrict__ agg, int n) {
    const int lane = threadIdx.x & 15;
    const int node = blockIdx.x * 16 + (threadIdx.x >> 4);
    if (node >= n) return;
    const int c0 = lane * 8;
    const float4 wla = *(const float4*)(wlast + c0);
    const float4 wlb = *(const float4*)(wlast + c0 + 4);
    const int p0 = rs[node], p1 = rs[node + 1];
    float a0=0,a1=0,a2=0,a3=0,a4=0,a5=0,a6=0,a7=0;
    int p = p0;
    for (; p + 4 <= p1; p += 4) {
        uint2 r[4];
#pragma unroll
        for (int u = 0; u < 4; ++u) r[u] = rec[p + u];
        uint4 G[4];
#pragma unroll
        for (int u = 0; u < 4; ++u) G[u] = *(const uint4*)(g + (long)r[u].x * HD + c0);
#pragma unroll
        for (int u = 0; u < 4; ++u) {
            const float e = __builtin_bit_cast(float, r[u].y);
            a0 += fmaxf(fmaf(e, wla.x, bflo(G[u].x)), 0.f);
            a1 += fmaxf(fmaf(e, wla.y, bfhi(G[u].x)), 0.f);
            a2 += fmaxf(fmaf(e, wla.z, bflo(G[u].y)), 0.f);
            a3 += fmaxf(fmaf(e, wla.w, bfhi(G[u].y)), 0.f);
            a4 += fmaxf(fmaf(e, wlb.x, bflo(G[u].z)), 0.f);
            a5 += fmaxf(fmaf(e, wlb.y, bfhi(G[u].z)), 0.f);
            a6 += fmaxf(fmaf(e, wlb.z, bflo(G[u].w)), 0.f);
            a7 += fmaxf(fmaf(e, wlb.w, bfhi(G[u].w)), 0.f);
        }
    }
    for (; p < p1; ++p) {
        const uint2 r0 = rec[p];
        const float e0 = __builtin_bit_cast(float, r0.y);
        const uint4 G0 = *(const uint4*)(g + (long)r0.x * HD + c0);
        a0 += fmaxf(fmaf(e0, wla.x, bflo(G0.x)), 0.f);
        a1 += fmaxf(fmaf(e0, wla.y, bfhi(G0.x)), 0.f);
        a2 += fmaxf(fmaf(e0, wla.z, bflo(G0.y)), 0.f);
        a3 += fmaxf(fmaf(e0, wla.w, bfhi(G0.y)), 0.f);
        a4 += fmaxf(fmaf(e0, wlb.x, bflo(G0.z)), 0.f);
        a5 += fmaxf(fmaf(e0, wlb.y, bfhi(G0.z)), 0.f);
        a6 += fmaxf(fmaf(e0, wlb.z, bflo(G0.w)), 0.f);
        a7 += fmaxf(fmaf(e0, wlb.w, bfhi(G0.w)), 0.f);
    }
    const float id = inv_deg[node];
    uint4 o;
    o.x = (unsigned)f2bf(a0 * id) | ((unsigned)f2bf(a1 * id) << 16);
    o.y = (unsigned)f2bf(a2 * id) | ((unsigned)f2bf(a3 * id) << 16);
    o.z = (unsigned)f2bf(a4 * id) | ((unsigned)f2bf(a5 * id) << 16);
    o.w = (unsigned)f2bf(a6 * id) | ((unsigned)f2bf(a7 * id) << 16);
    *(uint4*)(agg + (long)node * HD + c0) = o;
}

extern "C" void kernel_launch(void* const* d_in, const int* in_sizes, int n_in,
                              void* d_out, int out_size, void* d_ws, size_t ws_size,
                              hipStream_t stream)
{
    const float* x     = (const float*)d_in[0];
    const float* eattr = (const float*)d_in[1];
    const float* W_lin = (const float*)d_in[2];
    const float* b_lin = (const float*)d_in[3];
    const float* W_msg = (const float*)d_in[4];
    const float* b_msg = (const float*)d_in[5];
    const float* W_l   = (const float*)d_in[6];
    const float* b_l   = (const float*)d_in[7];
    const float* W_r   = (const float*)d_in[8];
    const float* W_dec = (const float*)d_in[9];
    const float* b_dec = (const float*)d_in[10];
    const float* W_fin = (const float*)d_in[11];
    const float* b_fin = (const float*)d_in[12];
    const int*   ei    = (const int*)d_in[13];

    const int N = in_sizes[0] / HD;   // 100000
    const int E = in_sizes[1];        // 600000
    const int* srcv = ei;
    const int* dstv = ei + E;

    char* wsb = (char*)d_ws;
    size_t off = 0;
    auto carve = [&](size_t bytes) -> void* {
        void* p = wsb + off;
        off += (bytes + 255) & ~(size_t)255;
        return p;
    };
    unsigned short* xb = (unsigned short*)carve((size_t)N * HD * 2);
    unsigned short* t1 = (unsigned short*)carve((size_t)N * HD * 2);
    unsigned short* t2 = (unsigned short*)carve((size_t)N * HD * 2);
    unsigned short* t3 = (unsigned short*)carve((size_t)N * HD * 2);
    unsigned short* wt = (unsigned short*)carve((size_t)14 * 16384 * 2);
    uint2* csr_rec  = (uint2*)carve((size_t)E * 8);
    int*   rowstart = (int*)carve((size_t)(N + 1) * 4);
    int*   deg      = (int*)carve((size_t)N * 4);
    float* inv_deg  = (float*)carve((size_t)N * 4);
    const int NCH = (N + 255) / 256;
    int* csum  = (int*)carve((size_t)NCH * 4);
    int* cbase = (int*)carve((size_t)NCH * 4);

    if (off > ws_size) {
        hipMemsetAsync(d_out, 0, (size_t)out_size * 4, stream);
        return;
    }

    hipMemsetAsync(deg, 0, (size_t)N * 4, stream);

    auto WT = [&](int m) { return wt + (size_t)m * 16384; };
    const int NB64 = (N + 63) / 64;
    const int GAGG = (N + 15) / 16;
    const long n8 = (long)N * HD / 8;
    const int ncast = (int)((n8 + 255) / 256);

    // U1: deg ∪ cast ∪ prep_w
    k_u1<<<NBLK_SCAT + ncast + 14 * 64, 256, 0, stream>>>(
        dstv, deg, E, x, xb, n8, ncast, W_lin, W_msg, W_l, W_r, W_dec, W_fin, wt, N);
    k_chunksum<<<NCH, 256, 0, stream>>>(deg, csum, N);
    k_scanmid<<<1, 512, 0, stream>>>(csum, cbase, rowstart, NCH, N);
    k_scan2<<<NCH, 256, 0, stream>>>(deg, cbase, rowstart, inv_deg, N);

    // U2: fill ∪ chain0 (xb -> g0 in t2)
    k_u2<<<NBLK_SCAT + NB64, 256, 0, stream>>>(
        srcv, dstv, eattr, rowstart, deg, csr_rec, E,
        xb, WT(0), WT(3), b_lin, b_msg, t2, N);

    auto wlast = [&](int l) { return W_msg + (size_t)l * (HD + 1) * HD + (size_t)HD * HD; };

    // Alias-free rotation: x path xb -> t3 -> xb ; g -> t2 ; agg -> t1.
    // agg0: g0(t2) -> t1
    k_agg<<<GAGG, 256, 0, stream>>>(t2, csr_rec, rowstart, inv_deg, wlast(0), t1, N);
    // dualchain l0->l1: Agg=t1, X=xb -> x1=t3, g1=t2 (g0 dead)
    k_dualchain<<<NB64, 256, 0, stream>>>(
        t1, xb, WT(6), WT(9), b_l, WT(1), b_lin + HD, WT(4), b_msg + HD, t3, t2, N);
    // agg1: g1(t2) -> t1 (agg0 dead)
    k_agg<<<GAGG, 256, 0, stream>>>(t2, csr_rec, rowstart, inv_deg, wlast(1), t1, N);
    // dualchain l1->l2: Agg=t1, X=t3 -> x2=xb (xb dead), g2=t2 (g1 dead)
    k_dualchain<<<NB64, 256, 0, stream>>>(
        t1, t3, WT(7), WT(10), b_l + HD, WT(2), b_lin + 2 * HD, WT(5), b_msg + 2 * HD, xb, t2, N);
    // agg2: g2(t2) -> t1 (agg1 dead)
    k_agg<<<GAGG, 256, 0, stream>>>(t2, csr_rec, rowstart, inv_deg, wlast(2), t1, N);
    // dual2 + decoder: Agg=t1, X=xb -> d_out
    k_dualdec<<<NB64, 256, 0, stream>>>(t1, xb, WT(8), WT(11), b_l + 2 * HD,
                                        WT(12), b_dec, WT(13), b_fin, (float*)d_out, N);
}

// Round 17
// 300.417 us; speedup vs baseline: 1.2471x; 1.0626x over previous
//
#include <hip/hip_runtime.h>

using short8 = __attribute__((ext_vector_type(8))) short;
using f32x4  = __attribute__((ext_vector_type(4))) float;

constexpr int HD = 128;
constexpr int NBLK_SCAT = 2048;   // scatter (deg/fill) blocks: 8 XCD groups x 256

__device__ __forceinline__ unsigned short f2bf(float f) {
    unsigned u = __builtin_bit_cast(unsigned, f);
    u += 0x7fffu + ((u >> 16) & 1u);          // round-to-nearest-even
    return (unsigned short)(u >> 16);
}
__device__ __forceinline__ float bflo(unsigned u) { return __builtin_bit_cast(float, u << 16); }
__device__ __forceinline__ float bfhi(unsigned u) { return __builtin_bit_cast(float, u & 0xffff0000u); }

__device__ __forceinline__ short8 ldg8(const unsigned short* p) {
    return *reinterpret_cast<const short8*>(p);   // 16B contiguous, aligned
}

// ---------------------------------------------------------------------------
// Chain GEMM body: Out = (relu(A @ Wt1 + b1)) @ Wtc + b2. 64 rows x 128 cols.
// Final output staged into As1 (dead after phase 1), then written coalesced
// (uint4) after an end-of-kernel barrier -- replaces 32 scalar 2B stores.
// ---------------------------------------------------------------------------
__device__ __forceinline__ void dev_chain(unsigned short* As1, unsigned short* Hs,
    const unsigned short* __restrict__ A, const unsigned short* __restrict__ Wt1,
    const unsigned short* __restrict__ Wtc, const float* __restrict__ b1,
    const float* __restrict__ b2, unsigned short* __restrict__ Out, int nrows, int bid)
{
    const int tid  = threadIdx.x;
    const int lane = tid & 63, wave = tid >> 6;
    const int lr = lane & 15, lg = lane >> 4;
    const int row0 = bid * 64;

#pragma unroll
    for (int it = 0; it < 4; ++it) {
        const int q   = wave * 4 + it;
        const int c   = q * 64 + lane;
        const int row = c >> 4, cw = c & 15;
        int grow = row0 + row; grow = grow < nrows ? grow : nrows - 1;
        const int gco = (cw ^ (row & 7)) << 3;
        __builtin_amdgcn_global_load_lds((const unsigned int*)(A + (long)grow * HD + gco),
                                         (unsigned int*)&As1[q * 512], 16, 0, 0);
    }

    const int cb = wave * 32;
    short8 bf1[2][4];
#pragma unroll
    for (int ct = 0; ct < 2; ++ct) {
        const unsigned short* bp = Wt1 + (long)(cb + ct * 16 + lr) * HD + lg * 8;
#pragma unroll
        for (int kt = 0; kt < 4; ++kt) bf1[ct][kt] = ldg8(bp + kt * 32);
    }
    short8 bfc[2][4];
#pragma unroll
    for (int ct = 0; ct < 2; ++ct) {
        const unsigned short* bp = Wtc + (long)(cb + ct * 16 + lr) * HD + lg * 8;
#pragma unroll
        for (int kt = 0; kt < 4; ++kt) bfc[ct][kt] = ldg8(bp + kt * 32);
    }

    __syncthreads();   // (1) DMA + weights drained

    f32x4 acc[4][2] = {};
#pragma unroll
    for (int kt = 0; kt < 4; ++kt) {
        short8 af[4];
#pragma unroll
        for (int rt = 0; rt < 4; ++rt)
            af[rt] = *reinterpret_cast<const short8*>(
                &As1[(rt * 16 + lr) * HD + (((kt * 4 + lg) ^ (lr & 7)) << 3)]);
#pragma unroll
        for (int rt = 0; rt < 4; ++rt)
#pragma unroll
            for (int ct = 0; ct < 2; ++ct)
                acc[rt][ct] = __builtin_amdgcn_mfma_f32_16x16x32_bf16(af[rt], bf1[ct][kt], acc[rt][ct], 0, 0, 0);
    }

    const float bv1[2] = { b1[cb + lr], b1[cb + 16 + lr] };
#pragma unroll
    for (int rt = 0; rt < 4; ++rt)
#pragma unroll
        for (int ct = 0; ct < 2; ++ct) {
            const int cc = cb + ct * 16 + lr;
#pragma unroll
            for (int i = 0; i < 4; ++i) {
                const int row = rt * 16 + lg * 4 + i;
                const float v = fmaxf(acc[rt][ct][i] + bv1[ct], 0.f);
                Hs[row * HD + ((((cc >> 3) ^ (row & 7)) << 3) | (cc & 7))] = f2bf(v);
            }
        }
    __syncthreads();   // (2) h visible; As1 reads all done

    f32x4 acc2[4][2] = {};
#pragma unroll
    for (int kt = 0; kt < 4; ++kt) {
        short8 ah[4];
#pragma unroll
        for (int rt = 0; rt < 4; ++rt)
            ah[rt] = *reinterpret_cast<const short8*>(
                &Hs[(rt * 16 + lr) * HD + (((kt * 4 + lg) ^ (lr & 7)) << 3)]);
#pragma unroll
        for (int rt = 0; rt < 4; ++rt)
#pragma unroll
            for (int ct = 0; ct < 2; ++ct)
                acc2[rt][ct] = __builtin_amdgcn_mfma_f32_16x16x32_bf16(ah[rt], bfc[ct][kt], acc2[rt][ct], 0, 0, 0);
    }
    const float bv2[2] = { b2[cb + lr], b2[cb + 16 + lr] };
    // stage result into As1 (dead), swizzled
#pragma unroll
    for (int rt = 0; rt < 4; ++rt)
#pragma unroll
        for (int ct = 0; ct < 2; ++ct) {
            const int cc = cb + ct * 16 + lr;
#pragma unroll
            for (int i = 0; i < 4; ++i) {
                const int row = rt * 16 + lg * 4 + i;
                As1[row * HD + ((((cc >> 3) ^ (row & 7)) << 3) | (cc & 7))] = f2bf(acc2[rt][ct][i] + bv2[ct]);
            }
        }
    __syncthreads();   // (3) staged output visible (off MFMA critical path)

    // coalesced uint4 write-out
#pragma unroll
    for (int k = 0; k < 4; ++k) {
        const int c   = tid + k * 256;
        const int row = c >> 4, cw = c & 15;
        const int r = row0 + row;
        if (r < nrows) {
            const uint4 v = *reinterpret_cast<const uint4*>(
                &As1[row * HD + ((cw ^ (row & 7)) << 3)]);
            *reinterpret_cast<uint4*>(Out + (long)r * HD + cw * 8) = v;
        }
    }
}

// ---------------------------------------------------------------------------
// Merged dual + next-layer chain (64-row blocks, 3 LDS buffers = 48KB):
//   phase1: x' = relu(Ag@WtL + Xs@WtR + bl) -> Ts (LDS only)
//   phase2: h  = relu(Ts@Wt1 + b1) -> Ag
//   phase3: g  = Ag@Wtc + b2 -> Xs (Xs dead since barrier 2)
//   tail : one barrier, then merged coalesced uint4 write-out:
//          Ts -> Xout (x'), Xs -> Gout (g)
// Caller guarantees Xout/Gout do not alias Agg/X.
// ---------------------------------------------------------------------------
__global__ __launch_bounds__(256)
void k_dualchain(const unsigned short* __restrict__ Agg, const unsigned short* __restrict__ X,
                 const unsigned short* __restrict__ WtL, const unsigned short* __restrict__ WtR,
                 const float* __restrict__ bl_,
                 const unsigned short* __restrict__ Wt1, const float* __restrict__ b1,
                 const unsigned short* __restrict__ Wtc, const float* __restrict__ b2,
                 unsigned short* __restrict__ Xout, unsigned short* __restrict__ Gout, int n)
{
    __shared__ __align__(16) unsigned short Ag[64 * HD];
    __shared__ __align__(16) unsigned short Xs[64 * HD];
    __shared__ __align__(16) unsigned short Ts[64 * HD];

    const int tid  = threadIdx.x;
    const int lane = tid & 63, wave = tid >> 6;
    const int lr = lane & 15, lg = lane >> 4;
    const int row0 = blockIdx.x * 64;

#pragma unroll
    for (int it = 0; it < 4; ++it) {
        const int q   = wave * 4 + it;
        const int c   = q * 64 + lane;
        const int row = c >> 4, cw = c & 15;
        int grow = row0 + row; grow = grow < n ? grow : n - 1;
        const int gco = (cw ^ (row & 7)) << 3;
        __builtin_amdgcn_global_load_lds((const unsigned int*)(Agg + (long)grow * HD + gco),
                                         (unsigned int*)&Ag[q * 512], 16, 0, 0);
        __builtin_amdgcn_global_load_lds((const unsigned int*)(X + (long)grow * HD + gco),
                                         (unsigned int*)&Xs[q * 512], 16, 0, 0);
    }

    const int cb = wave * 32;
    short8 bl[2][4], br[2][4];
#pragma unroll
    for (int ct = 0; ct < 2; ++ct) {
        const unsigned short* pl = WtL + (long)(cb + ct * 16 + lr) * HD + lg * 8;
        const unsigned short* pr = WtR + (long)(cb + ct * 16 + lr) * HD + lg * 8;
#pragma unroll
        for (int kt = 0; kt < 4; ++kt) { bl[ct][kt] = ldg8(pl + kt * 32); br[ct][kt] = ldg8(pr + kt * 32); }
    }
    __syncthreads();   // (1) DMA + weights drained

    // phase 1: x' = relu(Ag@WtL + Xs@WtR + bl) -> Ts (LDS only)
    {
        f32x4 acc[4][2] = {};
#pragma unroll
        for (int kt = 0; kt < 4; ++kt) {
            short8 aa[4], ax[4];
#pragma unroll
            for (int rt = 0; rt < 4; ++rt) {
                const int base = (rt * 16 + lr) * HD + (((kt * 4 + lg) ^ (lr & 7)) << 3);
                aa[rt] = *reinterpret_cast<const short8*>(&Ag[base]);
                ax[rt] = *reinterpret_cast<const short8*>(&Xs[base]);
            }
#pragma unroll
            for (int rt = 0; rt < 4; ++rt)
#pragma unroll
                for (int ct = 0; ct < 2; ++ct) {
                    acc[rt][ct] = __builtin_amdgcn_mfma_f32_16x16x32_bf16(aa[rt], bl[ct][kt], acc[rt][ct], 0, 0, 0);
                    acc[rt][ct] = __builtin_amdgcn_mfma_f32_16x16x32_bf16(ax[rt], br[ct][kt], acc[rt][ct], 0, 0, 0);
                }
        }
        const float bv[2] = { bl_[cb + lr], bl_[cb + 16 + lr] };
#pragma unroll
        for (int rt = 0; rt < 4; ++rt)
#pragma unroll
            for (int ct = 0; ct < 2; ++ct) {
                const int cc = cb + ct * 16 + lr;
#pragma unroll
                for (int i = 0; i < 4; ++i) {
                    const int row = rt * 16 + lg * 4 + i;
                    const float v = fmaxf(acc[rt][ct][i] + bv[ct], 0.f);
                    Ts[row * HD + ((((cc >> 3) ^ (row & 7)) << 3) | (cc & 7))] = f2bf(v);
                }
            }
    }
    __syncthreads();   // (2) Ts visible; all Ag/Xs reads done

    // phase 2: h = relu(Ts@Wt1 + b1) -> Ag
    {
        short8 b1f[2][4];
#pragma unroll
        for (int ct = 0; ct < 2; ++ct) {
            const unsigned short* bp = Wt1 + (long)(cb + ct * 16 + lr) * HD + lg * 8;
#pragma unroll
            for (int kt = 0; kt < 4; ++kt) b1f[ct][kt] = ldg8(bp + kt * 32);
        }
        f32x4 a2[4][2] = {};
#pragma unroll
        for (int kt = 0; kt < 4; ++kt) {
            short8 ah[4];
#pragma unroll
            for (int rt = 0; rt < 4; ++rt)
                ah[rt] = *reinterpret_cast<const short8*>(
                    &Ts[(rt * 16 + lr) * HD + (((kt * 4 + lg) ^ (lr & 7)) << 3)]);
#pragma unroll
            for (int rt = 0; rt < 4; ++rt)
#pragma unroll
                for (int ct = 0; ct < 2; ++ct)
                    a2[rt][ct] = __builtin_amdgcn_mfma_f32_16x16x32_bf16(ah[rt], b1f[ct][kt], a2[rt][ct], 0, 0, 0);
        }
        // issue phase-3 weights (hide under epilogue + barrier)
        short8 bcf[2][4];
#pragma unroll
        for (int ct = 0; ct < 2; ++ct) {
            const unsigned short* bp = Wtc + (long)(cb + ct * 16 + lr) * HD + lg * 8;
#pragma unroll
            for (int kt = 0; kt < 4; ++kt) bcf[ct][kt] = ldg8(bp + kt * 32);
        }
        const float bv[2] = { b1[cb + lr], b1[cb + 16 + lr] };
#pragma unroll
        for (int rt = 0; rt < 4; ++rt)
#pragma unroll
            for (int ct = 0; ct < 2; ++ct) {
                const int cc = cb + ct * 16 + lr;
#pragma unroll
                for (int i = 0; i < 4; ++i) {
                    const int row = rt * 16 + lg * 4 + i;
                    const float v = fmaxf(a2[rt][ct][i] + bv[ct], 0.f);
                    Ag[row * HD + ((((cc >> 3) ^ (row & 7)) << 3) | (cc & 7))] = f2bf(v);
                }
            }
        __syncthreads();   // (3) h visible

        // phase 3: g = Ag@Wtc + b2 -> Xs (dead since barrier 2)
        f32x4 a3[4][2] = {};
#pragma unroll
        for (int kt = 0; kt < 4; ++kt) {
            short8 ah[4];
#pragma unroll
            for (int rt = 0; rt < 4; ++rt)
                ah[rt] = *reinterpret_cast<const short8*>(
                    &Ag[(rt * 16 + lr) * HD + (((kt * 4 + lg) ^ (lr & 7)) << 3)]);
#pragma unroll
            for (int rt = 0; rt < 4; ++rt)
#pragma unroll
                for (int ct = 0; ct < 2; ++ct)
                    a3[rt][ct] = __builtin_amdgcn_mfma_f32_16x16x32_bf16(ah[rt], bcf[ct][kt], a3[rt][ct], 0, 0, 0);
        }
        const float bv2[2] = { b2[cb + lr], b2[cb + 16 + lr] };
#pragma unroll
        for (int rt = 0; rt < 4; ++rt)
#pragma unroll
            for (int ct = 0; ct < 2; ++ct) {
                const int cc = cb + ct * 16 + lr;
#pragma unroll
                for (int i = 0; i < 4; ++i) {
                    const int row = rt * 16 + lg * 4 + i;
                    Xs[row * HD + ((((cc >> 3) ^ (row & 7)) << 3) | (cc & 7))] = f2bf(a3[rt][ct][i] + bv2[ct]);
                }
            }
    }
    __syncthreads();   // (4) staged outputs visible (off MFMA critical path)

    // merged coalesced write-out: Ts -> Xout (x'), Xs -> Gout (g)
#pragma unroll
    for (int k = 0; k < 4; ++k) {
        const int c   = tid + k * 256;
        const int row = c >> 4, cw = c & 15;
        const int r = row0 + row;
        if (r < n) {
            const int off = row * HD + ((cw ^ (row & 7)) << 3);
            *reinterpret_cast<uint4*>(Xout + (long)r * HD + cw * 8) =
                *reinterpret_cast<const uint4*>(&Ts[off]);
            *reinterpret_cast<uint4*>(Gout + (long)r * HD + cw * 8) =
                *reinterpret_cast<const uint4*>(&Xs[off]);
        }
    }
}

// ---------------------------------------------------------------------------
// Merged dual + decoder (64-row blocks, 3 LDS buffers):
//   phase1: x3 = relu(Ag@WtL + Xs@WtR + bl) -> Ts
//   phase2: emb = relu(Ts@Wdec + bdec) -> Ag
//   phase3: logits = Ag@Wfin + bfin -> f32 out (direct; f32 row stores are 64B)
// ---------------------------------------------------------------------------
__global__ __launch_bounds__(256)
void k_dualdec(const unsigned short* __restrict__ Agg, const unsigned short* __restrict__ X,
               const unsigned short* __restrict__ WtL, const unsigned short* __restrict__ WtR,
               const float* __restrict__ bl_, const unsigned short* __restrict__ Wdec,
               const float* __restrict__ bdec, const unsigned short* __restrict__ Wfin,
               const float* __restrict__ bfin, float* __restrict__ Out, int n)
{
    __shared__ __align__(16) unsigned short Ag[64 * HD];
    __shared__ __align__(16) unsigned short Xs[64 * HD];
    __shared__ __align__(16) unsigned short Ts[64 * HD];

    const int tid  = threadIdx.x;
    const int lane = tid & 63, wave = tid >> 6;
    const int lr = lane & 15, lg = lane >> 4;
    const int row0 = blockIdx.x * 64;

#pragma unroll
    for (int it = 0; it < 4; ++it) {
        const int q   = wave * 4 + it;
        const int c   = q * 64 + lane;
        const int row = c >> 4, cw = c & 15;
        int grow = row0 + row; grow = grow < n ? grow : n - 1;
        const int gco = (cw ^ (row & 7)) << 3;
        __builtin_amdgcn_global_load_lds((const unsigned int*)(Agg + (long)grow * HD + gco),
                                         (unsigned int*)&Ag[q * 512], 16, 0, 0);
        __builtin_amdgcn_global_load_lds((const unsigned int*)(X + (long)grow * HD + gco),
                                         (unsigned int*)&Xs[q * 512], 16, 0, 0);
    }

    const int cb = wave * 32;
    short8 bl[2][4], br[2][4];
#pragma unroll
    for (int ct = 0; ct < 2; ++ct) {
        const unsigned short* pl = WtL + (long)(cb + ct * 16 + lr) * HD + lg * 8;
        const unsigned short* pr = WtR + (long)(cb + ct * 16 + lr) * HD + lg * 8;
#pragma unroll
        for (int kt = 0; kt < 4; ++kt) { bl[ct][kt] = ldg8(pl + kt * 32); br[ct][kt] = ldg8(pr + kt * 32); }
    }
    __syncthreads();   // (1)

    // phase 1: x3 = relu(Ag@WtL + Xs@WtR + bl) -> Ts (swizzled)
    {
        f32x4 acc[4][2] = {};
#pragma unroll
        for (int kt = 0; kt < 4; ++kt) {
            short8 aa[4], ax[4];
#pragma unroll
            for (int rt = 0; rt < 4; ++rt) {
                const int base = (rt * 16 + lr) * HD + (((kt * 4 + lg) ^ (lr & 7)) << 3);
                aa[rt] = *reinterpret_cast<const short8*>(&Ag[base]);
                ax[rt] = *reinterpret_cast<const short8*>(&Xs[base]);
            }
#pragma unroll
            for (int rt = 0; rt < 4; ++rt)
#pragma unroll
                for (int ct = 0; ct < 2; ++ct) {
                    acc[rt][ct] = __builtin_amdgcn_mfma_f32_16x16x32_bf16(aa[rt], bl[ct][kt], acc[rt][ct], 0, 0, 0);
                    acc[rt][ct] = __builtin_amdgcn_mfma_f32_16x16x32_bf16(ax[rt], br[ct][kt], acc[rt][ct], 0, 0, 0);
                }
        }
        const float bv[2] = { bl_[cb + lr], bl_[cb + 16 + lr] };
#pragma unroll
        for (int rt = 0; rt < 4; ++rt)
#pragma unroll
            for (int ct = 0; ct < 2; ++ct) {
                const int cc = cb + ct * 16 + lr;
#pragma unroll
                for (int i = 0; i < 4; ++i) {
                    const int row = rt * 16 + lg * 4 + i;
                    const float v = fmaxf(acc[rt][ct][i] + bv[ct], 0.f);
                    Ts[row * HD + ((((cc >> 3) ^ (row & 7)) << 3) | (cc & 7))] = f2bf(v);
                }
            }
    }
    __syncthreads();   // (2)

    // phase 2: emb = relu(Ts@Wdec + bdec) -> Ag (Ag reads all done)
    {
        short8 bd[2][4];
#pragma unroll
        for (int ct = 0; ct < 2; ++ct) {
            const unsigned short* bp = Wdec + (long)(cb + ct * 16 + lr) * HD + lg * 8;
#pragma unroll
            for (int kt = 0; kt < 4; ++kt) bd[ct][kt] = ldg8(bp + kt * 32);
        }
        f32x4 a2[4][2] = {};
#pragma unroll
        for (int kt = 0; kt < 4; ++kt) {
            short8 ah[4];
#pragma unroll
            for (int rt = 0; rt < 4; ++rt)
                ah[rt] = *reinterpret_cast<const short8*>(
                    &Ts[(rt * 16 + lr) * HD + (((kt * 4 + lg) ^ (lr & 7)) << 3)]);
#pragma unroll
            for (int rt = 0; rt < 4; ++rt)
#pragma unroll
                for (int ct = 0; ct < 2; ++ct)
                    a2[rt][ct] = __builtin_amdgcn_mfma_f32_16x16x32_bf16(ah[rt], bd[ct][kt], a2[rt][ct], 0, 0, 0);
        }
        const int cbf = wave * 16;
        short8 bfn[4];
#pragma unroll
        for (int kt = 0; kt < 4; ++kt)
            bfn[kt] = ldg8(Wfin + (long)(cbf + lr) * HD + lg * 8 + kt * 32);
        const float bv[2] = { bdec[cb + lr], bdec[cb + 16 + lr] };
#pragma unroll
        for (int rt = 0; rt < 4; ++rt)
#pragma unroll
            for (int ct = 0; ct < 2; ++ct) {
                const int cc = cb + ct * 16 + lr;
#pragma unroll
                for (int i = 0; i < 4; ++i) {
                    const int row = rt * 16 + lg * 4 + i;
                    const float v = fmaxf(a2[rt][ct][i] + bv[ct], 0.f);
                    Ag[row * HD + ((((cc >> 3) ^ (row & 7)) << 3) | (cc & 7))] = f2bf(v);
                }
            }
        __syncthreads();   // (3)

        // phase 3: logits = Ag@Wfin + bfin -> f32 (64 cols; wave covers 16)
        f32x4 a3[4] = {};
#pragma unroll
        for (int kt = 0; kt < 4; ++kt) {
            short8 ah[4];
#pragma unroll
            for (int rt = 0; rt < 4; ++rt)
                ah[rt] = *reinterpret_cast<const short8*>(
                    &Ag[(rt * 16 + lr) * HD + (((kt * 4 + lg) ^ (lr & 7)) << 3)]);
#pragma unroll
            for (int rt = 0; rt < 4; ++rt)
                a3[rt] = __builtin_amdgcn_mfma_f32_16x16x32_bf16(ah[rt], bfn[kt], a3[rt], 0, 0, 0);
        }
        const float bvf = bfin[cbf + lr];
#pragma unroll
        for (int rt = 0; rt < 4; ++rt)
#pragma unroll
            for (int i = 0; i < 4; ++i) {
                const int r = row0 + rt * 16 + lg * 4 + i;
                if (r < n) Out[(long)r * 64 + cbf + lr] = a3[rt][i] + bvf;
            }
    }
}

// ---- scatter bodies (XCD-affine: 8 node-chunks, group = bid&7) ----
__device__ __forceinline__ void dev_deg(const int* __restrict__ dst, int* __restrict__ deg,
                                        int nE, int n, int bid, int nblk) {
    const int grp = bid & 7, bin = bid >> 3, nbin = nblk >> 3;
    const int chunk = (n + 7) >> 3;
    const int lo = grp * chunk, hi = min(n, lo + chunk);
    for (int e = bin * 256 + threadIdx.x; e < nE; e += nbin * 256) {
        const int d = dst[e];
        if (d >= lo && d < hi) atomicAdd(&deg[d], 1);
    }
}

__device__ __forceinline__ void dev_fill(const int* __restrict__ src, const int* __restrict__ dst,
                                         const float* __restrict__ eattr, const int* __restrict__ rowstart,
                                         int* __restrict__ degcur, uint2* __restrict__ csr_rec,
                                         int nE, int n, int bid, int nblk) {
    const int grp = bid & 7, bin = bid >> 3, nbin = nblk >> 3;
    const int chunk = (n + 7) >> 3;
    const int lo = grp * chunk, hi = min(n, lo + chunk);
    for (int e = bin * 256 + threadIdx.x; e < nE; e += nbin * 256) {
        const int d = dst[e];
        if (d >= lo && d < hi) {
            const int p = rowstart[d] + atomicSub(&degcur[d], 1) - 1;
            uint2 rec;
            rec.x = (unsigned)src[e];
            rec.y = __builtin_bit_cast(unsigned, eattr[e]);
            csr_rec[p] = rec;
        }
    }
}

// ---- U1: deg ∪ cast(x->bf16) ∪ prep_w ----
__global__ __launch_bounds__(256)
void k_u1(const int* __restrict__ dst, int* __restrict__ deg, int nE,
          const float* __restrict__ xin, unsigned short* __restrict__ xb, long n8, int ncast,
          const float* __restrict__ Wlin, const float* __restrict__ Wmsg,
          const float* __restrict__ Wl,   const float* __restrict__ Wr,
          const float* __restrict__ Wdec, const float* __restrict__ Wfin,
          unsigned short* __restrict__ wt, int n)
{
    const int bid = blockIdx.x;
    if (bid < NBLK_SCAT) { dev_deg(dst, deg, nE, n, bid, NBLK_SCAT); return; }
    const int b = bid - NBLK_SCAT;
    if (b < ncast) {
        const long i = (long)b * 256 + threadIdx.x;
        if (i >= n8) return;
        const float4 v0 = *((const float4*)xin + i * 2);
        const float4 v1 = *((const float4*)xin + i * 2 + 1);
        unsigned o[4];
        o[0] = (unsigned)f2bf(v0.x) | ((unsigned)f2bf(v0.y) << 16);
        o[1] = (unsigned)f2bf(v0.z) | ((unsigned)f2bf(v0.w) << 16);
        o[2] = (unsigned)f2bf(v1.x) | ((unsigned)f2bf(v1.y) << 16);
        o[3] = (unsigned)f2bf(v1.z) | ((unsigned)f2bf(v1.w) << 16);
        *(uint4*)(xb + i * 8) = *(uint4*)o;
        return;
    }
    // prep_w: m: 0-2 W_lin, 3-5 W_msg(top 128), 6-8 W_l, 9-11 W_r, 12 W_dec, 13 W_fin(C=64)
    const int local = b - ncast;
    const int m = local >> 6;
    const float* src; int C = 128;
    if      (m < 3)  src = Wlin + m * 16384;
    else if (m < 6)  src = Wmsg + (m - 3) * (129 * 128);
    else if (m < 9)  src = Wl   + (m - 6) * 16384;
    else if (m < 12) src = Wr   + (m - 9) * 16384;
    else if (m == 12) src = Wdec;
    else { src = Wfin; C = 64; }
    const int elems = C * 128;
    const int e = (local & 63) * 256 + threadIdx.x;
    if (e >= elems) return;
    const int c = e >> 7, k = e & 127;
    wt[m * 16384 + e] = f2bf(src[k * C + c]);
}

// ---- U2: fill ∪ chain0 (fill blocks first to keep &7 XCD affinity) ----
__global__ __launch_bounds__(256)
void k_u2(const int* __restrict__ src, const int* __restrict__ dst,
          const float* __restrict__ eattr, const int* __restrict__ rowstart,
          int* __restrict__ degcur, uint2* __restrict__ csr_rec, int nE,
          const unsigned short* __restrict__ A, const unsigned short* __restrict__ Wt1,
          const unsigned short* __restrict__ Wtc, const float* __restrict__ b1,
          const float* __restrict__ b2, unsigned short* __restrict__ Out, int n)
{
    __shared__ __align__(16) unsigned short As1[64 * HD];
    __shared__ __align__(16) unsigned short Hs [64 * HD];
    if (blockIdx.x < NBLK_SCAT) {
        dev_fill(src, dst, eattr, rowstart, degcur, csr_rec, nE, n, blockIdx.x, NBLK_SCAT);
        return;
    }
    dev_chain(As1, Hs, A, Wt1, Wtc, b1, b2, Out, n, blockIdx.x - NBLK_SCAT);
}

// ---- scans ----
__global__ void k_chunksum(const int* __restrict__ deg, int* __restrict__ csum, int n) {
    __shared__ int s[256];
    int t = threadIdx.x, i = blockIdx.x * 256 + t;
    s[t] = (i < n) ? deg[i] : 0;
    __syncthreads();
    for (int o = 128; o > 0; o >>= 1) { if (t < o) s[t] += s[t + o]; __syncthreads(); }
    if (t == 0) csum[blockIdx.x] = s[0];
}

__global__ void k_scanmid(const int* __restrict__ csum, int* __restrict__ cbase,
                          int* __restrict__ rowstart, int nch, int n) {
    __shared__ int s[512];
    int t = threadIdx.x;
    int v = (t < nch) ? csum[t] : 0;
    s[t] = v; __syncthreads();
    for (int off = 1; off < 512; off <<= 1) {
        int tmp = (t >= off) ? s[t - off] : 0;
        __syncthreads();
        s[t] += tmp;
        __syncthreads();
    }
    if (t < nch) cbase[t] = s[t] - v;
    if (t == nch - 1) rowstart[n] = s[t];
}

__global__ void k_scan2(const int* __restrict__ deg, const int* __restrict__ cbase,
                        int* __restrict__ rowstart, float* __restrict__ inv_deg, int n) {
    __shared__ int s[256];
    int t = threadIdx.x, i = blockIdx.x * 256 + t;
    int v = (i < n) ? deg[i] : 0;
    s[t] = v; __syncthreads();
    for (int off = 1; off < 256; off <<= 1) {
        int tmp = (t >= off) ? s[t - off] : 0;
        __syncthreads();
        s[t] += tmp;
        __syncthreads();
    }
    if (i < n) {
        rowstart[i] = cbase[blockIdx.x] + s[t] - v;
        inv_deg[i] = 1.0f / fmaxf((float)v, 1.0f);
    }
}

// agg[i] = bf16( inv_deg[i] * sum_p relu(g[src_p] + attr_p * wlast) )
// 16 lanes/node, 16B/lane, 4-edge unroll.
__global__ __launch_bounds__(256)
void k_agg(const unsigned short* __restrict__ g, const uint2* __restrict__ rec,
           const int* __restrict__ rs, const float* __restrict__ inv_deg,
           const float* __restrict__ wlast, unsigned short* __restrict__ agg, int n) {
    const int lane = threadIdx.x & 15;
    const int node = blockIdx.x * 16 + (threadIdx.x >> 4);
    if (node >= n) return;
    const int c0 = lane * 8;
    const float4 wla = *(const float4*)(wlast + c0);
    const float4 wlb = *(const float4*)(wlast + c0 + 4);
    const int p0 = rs[node], p1 = rs[node + 1];
    float a0=0,a1=0,a2=0,a3=0,a4=0,a5=0,a6=0,a7=0;
    int p = p0;
    for (; p + 4 <= p1; p += 4) {
        uint2 r[4];
#pragma unroll
        for (int u = 0; u < 4; ++u) r[u] = rec[p + u];
        uint4 G[4];
#pragma unroll
        for (int u = 0; u < 4; ++u) G[u] = *(const uint4*)(g + (long)r[u].x * HD + c0);
#pragma unroll
        for (int u = 0; u < 4; ++u) {
            const float e = __builtin_bit_cast(float, r[u].y);
            a0 += fmaxf(fmaf(e, wla.x, bflo(G[u].x)), 0.f);
            a1 += fmaxf(fmaf(e, wla.y, bfhi(G[u].x)), 0.f);
            a2 += fmaxf(fmaf(e, wla.z, bflo(G[u].y)), 0.f);
            a3 += fmaxf(fmaf(e, wla.w, bfhi(G[u].y)), 0.f);
            a4 += fmaxf(fmaf(e, wlb.x, bflo(G[u].z)), 0.f);
            a5 += fmaxf(fmaf(e, wlb.y, bfhi(G[u].z)), 0.f);
            a6 += fmaxf(fmaf(e, wlb.z, bflo(G[u].w)), 0.f);
            a7 += fmaxf(fmaf(e, wlb.w, bfhi(G[u].w)), 0.f);
        }
    }
    for (; p < p1; ++p) {
        const uint2 r0 = rec[p];
        const float e0 = __builtin_bit_cast(float, r0.y);
        const uint4 G0 = *(const uint4*)(g + (long)r0.x * HD + c0);
        a0 += fmaxf(fmaf(e0, wla.x, bflo(G0.x)), 0.f);
        a1 += fmaxf(fmaf(e0, wla.y, bfhi(G0.x)), 0.f);
        a2 += fmaxf(fmaf(e0, wla.z, bflo(G0.y)), 0.f);
        a3 += fmaxf(fmaf(e0, wla.w, bfhi(G0.y)), 0.f);
        a4 += fmaxf(fmaf(e0, wlb.x, bflo(G0.z)), 0.f);
        a5 += fmaxf(fmaf(e0, wlb.y, bfhi(G0.z)), 0.f);
        a6 += fmaxf(fmaf(e0, wlb.z, bflo(G0.w)), 0.f);
        a7 += fmaxf(fmaf(e0, wlb.w, bfhi(G0.w)), 0.f);
    }
    const float id = inv_deg[node];
    uint4 o;
    o.x = (unsigned)f2bf(a0 * id) | ((unsigned)f2bf(a1 * id) << 16);
    o.y = (unsigned)f2bf(a2 * id) | ((unsigned)f2bf(a3 * id) << 16);
    o.z = (unsigned)f2bf(a4 * id) | ((unsigned)f2bf(a5 * id) << 16);
    o.w = (unsigned)f2bf(a6 * id) | ((unsigned)f2bf(a7 * id) << 16);
    *(uint4*)(agg + (long)node * HD + c0) = o;
}

extern "C" void kernel_launch(void* const* d_in, const int* in_sizes, int n_in,
                              void* d_out, int out_size, void* d_ws, size_t ws_size,
                              hipStream_t stream)
{
    const float* x     = (const float*)d_in[0];
    const float* eattr = (const float*)d_in[1];
    const float* W_lin = (const float*)d_in[2];
    const float* b_lin = (const float*)d_in[3];
    const float* W_msg = (const float*)d_in[4];
    const float* b_msg = (const float*)d_in[5];
    const float* W_l   = (const float*)d_in[6];
    const float* b_l   = (const float*)d_in[7];
    const float* W_r   = (const float*)d_in[8];
    const float* W_dec = (const float*)d_in[9];
    const float* b_dec = (const float*)d_in[10];
    const float* W_fin = (const float*)d_in[11];
    const float* b_fin = (const float*)d_in[12];
    const int*   ei    = (const int*)d_in[13];

    const int N = in_sizes[0] / HD;   // 100000
    const int E = in_sizes[1];        // 600000
    const int* srcv = ei;
    const int* dstv = ei + E;

    char* wsb = (char*)d_ws;
    size_t off = 0;
    auto carve = [&](size_t bytes) -> void* {
        void* p = wsb + off;
        off += (bytes + 255) & ~(size_t)255;
        return p;
    };
    unsigned short* xb = (unsigned short*)carve((size_t)N * HD * 2);
    unsigned short* t1 = (unsigned short*)carve((size_t)N * HD * 2);
    unsigned short* t2 = (unsigned short*)carve((size_t)N * HD * 2);
    unsigned short* t3 = (unsigned short*)carve((size_t)N * HD * 2);
    unsigned short* wt = (unsigned short*)carve((size_t)14 * 16384 * 2);
    uint2* csr_rec  = (uint2*)carve((size_t)E * 8);
    int*   rowstart = (int*)carve((size_t)(N + 1) * 4);
    int*   deg      = (int*)carve((size_t)N * 4);
    float* inv_deg  = (float*)carve((size_t)N * 4);
    const int NCH = (N + 255) / 256;
    int* csum  = (int*)carve((size_t)NCH * 4);
    int* cbase = (int*)carve((size_t)NCH * 4);

    if (off > ws_size) {
        hipMemsetAsync(d_out, 0, (size_t)out_size * 4, stream);
        return;
    }

    hipMemsetAsync(deg, 0, (size_t)N * 4, stream);

    auto WT = [&](int m) { return wt + (size_t)m * 16384; };
    const int NB64 = (N + 63) / 64;
    const int GAGG = (N + 15) / 16;
    const long n8 = (long)N * HD / 8;
    const int ncast = (int)((n8 + 255) / 256);

    // U1: deg ∪ cast ∪ prep_w
    k_u1<<<NBLK_SCAT + ncast + 14 * 64, 256, 0, stream>>>(
        dstv, deg, E, x, xb, n8, ncast, W_lin, W_msg, W_l, W_r, W_dec, W_fin, wt, N);
    k_chunksum<<<NCH, 256, 0, stream>>>(deg, csum, N);
    k_scanmid<<<1, 512, 0, stream>>>(csum, cbase, rowstart, NCH, N);
    k_scan2<<<NCH, 256, 0, stream>>>(deg, cbase, rowstart, inv_deg, N);

    // U2: fill ∪ chain0 (xb -> g0 in t2)
    k_u2<<<NBLK_SCAT + NB64, 256, 0, stream>>>(
        srcv, dstv, eattr, rowstart, deg, csr_rec, E,
        xb, WT(0), WT(3), b_lin, b_msg, t2, N);

    auto wlast = [&](int l) { return W_msg + (size_t)l * (HD + 1) * HD + (size_t)HD * HD; };

    // Alias-free rotation: x path xb -> t3 -> xb ; g -> t2 ; agg -> t1.
    // agg0: g0(t2) -> t1
    k_agg<<<GAGG, 256, 0, stream>>>(t2, csr_rec, rowstart, inv_deg, wlast(0), t1, N);
    // dualchain l0->l1: Agg=t1, X=xb -> x1=t3, g1=t2 (g0 dead)
    k_dualchain<<<NB64, 256, 0, stream>>>(
        t1, xb, WT(6), WT(9), b_l, WT(1), b_lin + HD, WT(4), b_msg + HD, t3, t2, N);
    // agg1: g1(t2) -> t1 (agg0 dead)
    k_agg<<<GAGG, 256, 0, stream>>>(t2, csr_rec, rowstart, inv_deg, wlast(1), t1, N);
    // dualchain l1->l2: Agg=t1, X=t3 -> x2=xb (xb dead), g2=t2 (g1 dead)
    k_dualchain<<<NB64, 256, 0, stream>>>(
        t1, t3, WT(7), WT(10), b_l + HD, WT(2), b_lin + 2 * HD, WT(5), b_msg + 2 * HD, xb, t2, N);
    // agg2: g2(t2) -> t1 (agg1 dead)
    k_agg<<<GAGG, 256, 0, stream>>>(t2, csr_rec, rowstart, inv_deg, wlast(2), t1, N);
    // dual2 + decoder: Agg=t1, X=xb -> d_out
    k_dualdec<<<NB64, 256, 0, stream>>>(t1, xb, WT(8), WT(11), b_l + 2 * HD,
                                        WT(12), b_dec, WT(13), b_fin, (float*)d_out, N);
}